// Round 5
// baseline (1032.058 us; speedup 1.0000x reference)
//
#include <hip/hip_runtime.h>

// ---------------------------------------------------------------------------
// MultiHeadsLinearAttention  (B=8, C=512, HEADS=8, CH=64, H=W=64 -> N=4096)
// Inputs: fp32 (sniffed, bf16-passthrough supported). Output: fp32.
// Compute: bf16 MFMA with fp32 accumulation.
//
// Per batch b (on canonical bf16 buffers):
//  C : QKV GEMM qkv[o][p] = invx[p]*sum_c (W[o][c]*g[c]) * x[c][p]  (MFMA)
//  D : k-softmax stats per channel row (kmax, kinv) + zero attnT
//  E : attnT[h][d][c] += sum_p exp(k[c][p]-kmax)*v[d][p]           (MFMA)
//  F : q-softmax over c per token; xoT[p][h*64+d] = qsm @ (attn*kinv)
//  G : FFN GEMM y[o][p] = ffn_b[o] + sum_c ffn_w[o][c]*xoT[p][c]
//  H1: invn2[p] = 1/||y[:,p]|| ;  H2: out = y*invn2*g2*sqrtC + x   (fp32 out)
// ---------------------------------------------------------------------------

typedef __bf16 bf16_t;
typedef __bf16 bf8 __attribute__((ext_vector_type(8)));
typedef float f32x4 __attribute__((ext_vector_type(4)));

#define NC 512
#define NP 4096
#define SQRTC 22.62741699796952f
#define QSCALE 0.125f
#define LDP 88

__device__ inline unsigned short bfbits(__bf16 h) {
    return __builtin_bit_cast(unsigned short, h);
}
__device__ inline __bf16 bits2bf(unsigned short u) {
    return __builtin_bit_cast(__bf16, u);
}

// ---------------------------------------------------------------------------
// Convert: src (bf16 or fp32, sniffed from gref) -> bf16 dst. 4 elems/thread.
// gref = norm_g (exactly ones): first uint16 0x3F80 iff bf16.
// ---------------------------------------------------------------------------
__global__ __launch_bounds__(256) void
convert_kernel(const void* __restrict__ src, bf16_t* __restrict__ dst, int n,
               const void* __restrict__ gref) {
    const bool isf32 = (((const unsigned short*)gref)[0] != 0x3F80u);
    int i0 = (blockIdx.x * 256 + threadIdx.x) * 4;
    if (i0 >= n) return;
    if (isf32) {
        const float* s = (const float*)src;
        float4 v = *(const float4*)&s[i0];
        ushort4 o;
        o.x = bfbits((__bf16)v.x);
        o.y = bfbits((__bf16)v.y);
        o.z = bfbits((__bf16)v.z);
        o.w = bfbits((__bf16)v.w);
        *(ushort4*)&dst[i0] = o;
    } else {
        *(ushort4*)&dst[i0] = *(const ushort4*)&((const bf16_t*)src)[i0];
    }
}

// ---------------------------------------------------------------------------
// C: QKV GEMM, one batch. grid(32, 12) block 256.
// A = qkv_w rows scaled by g during staging; B = x[c][p] transposed in LDS;
// per-token sumsq accumulated during staging -> invx in epilogue.
// ---------------------------------------------------------------------------
__global__ __launch_bounds__(256) void
gemm_qkv_kernel(const bf16_t* __restrict__ Wq, const bf16_t* __restrict__ g,
                const bf16_t* __restrict__ xb, bf16_t* __restrict__ qkv) {
    const int bn = blockIdx.x, bm = blockIdx.y;
    const int t = threadIdx.x;
    const int w = t >> 6, ln = t & 63, quad = ln >> 4, l16 = ln & 15;
    const int wm = w >> 1, wn = w & 1;

    __shared__ __align__(16) __bf16 sA[128][LDP];
    __shared__ __align__(16) __bf16 sB[128][LDP];
    __shared__ float sSS[256];
    __shared__ float sInvN[128];

    f32x4 acc[4][4] = {};
    float ss = 0.f;

    const bf16_t* Abase = Wq + (size_t)(bm * 128) * NC;
    const int p0 = bn * 128;

    for (int kt = 0; kt < 8; ++kt) {
        const int k0 = kt * 64;
        #pragma unroll
        for (int i = 0; i < 8; ++i) {
            int idx = t + i * 256;            // < 2048
            int r = idx >> 4;
            int c4 = (idx & 15) * 4;
            ushort4 wv = *(const ushort4*)&Abase[(size_t)r * NC + k0 + c4];
            ushort4 gv = *(const ushort4*)&g[k0 + c4];
            ushort4 o;
            o.x = bfbits((__bf16)((float)bits2bf(wv.x) * (float)bits2bf(gv.x)));
            o.y = bfbits((__bf16)((float)bits2bf(wv.y) * (float)bits2bf(gv.y)));
            o.z = bfbits((__bf16)((float)bits2bf(wv.z) * (float)bits2bf(gv.z)));
            o.w = bfbits((__bf16)((float)bits2bf(wv.w) * (float)bits2bf(gv.w)));
            *(ushort4*)&sA[r][c4] = o;
        }
        #pragma unroll
        for (int i = 0; i < 8; ++i) {
            int idx = t + i * 256;            // < 2048
            int pp = idx & 127;               // constant per thread
            int c0 = (idx >> 7) * 4;
            ushort4 u;
            u.x = bfbits(xb[(size_t)(k0 + c0 + 0) * NP + p0 + pp]);
            u.y = bfbits(xb[(size_t)(k0 + c0 + 1) * NP + p0 + pp]);
            u.z = bfbits(xb[(size_t)(k0 + c0 + 2) * NP + p0 + pp]);
            u.w = bfbits(xb[(size_t)(k0 + c0 + 3) * NP + p0 + pp]);
            float v0 = (float)bits2bf(u.x), v1 = (float)bits2bf(u.y);
            float v2 = (float)bits2bf(u.z), v3 = (float)bits2bf(u.w);
            ss += v0 * v0 + v1 * v1 + v2 * v2 + v3 * v3;
            *(ushort4*)&sB[pp][c0] = u;
        }
        __syncthreads();
        #pragma unroll
        for (int ks = 0; ks < 2; ++ks) {
            const int kk = ks * 32;
            bf8 af[4], bfr[4];
            #pragma unroll
            for (int mi = 0; mi < 4; ++mi)
                af[mi] = *(const bf8*)&sA[wm * 64 + mi * 16 + l16][kk + quad * 8];
            #pragma unroll
            for (int ni = 0; ni < 4; ++ni)
                bfr[ni] = *(const bf8*)&sB[wn * 64 + ni * 16 + l16][kk + quad * 8];
            #pragma unroll
            for (int mi = 0; mi < 4; ++mi)
                #pragma unroll
                for (int ni = 0; ni < 4; ++ni)
                    acc[mi][ni] = __builtin_amdgcn_mfma_f32_16x16x32_bf16(
                        af[mi], bfr[ni], acc[mi][ni], 0, 0, 0);
        }
        __syncthreads();
    }

    // threads t and t+128 hold complementary halves of column (t&127)'s sumsq
    sSS[t] = ss;
    __syncthreads();
    if (t < 128)
        sInvN[t] = SQRTC / fmaxf(sqrtf(sSS[t] + sSS[t + 128]), 1e-12f);
    __syncthreads();

    #pragma unroll
    for (int ni = 0; ni < 4; ++ni) {
        const int colL = wn * 64 + ni * 16 + l16;
        const float sc = sInvN[colL];
        #pragma unroll
        for (int mi = 0; mi < 4; ++mi) {
            #pragma unroll
            for (int r = 0; r < 4; ++r) {
                const int row = bm * 128 + wm * 64 + mi * 16 + quad * 4 + r;
                qkv[(size_t)row * NP + p0 + colL] = (__bf16)(acc[mi][ni][r] * sc);
            }
        }
    }
}

// ---------------------------------------------------------------------------
// D: k-softmax stats per channel row, one batch. grid(512) block 256.
// Blocks [0,128) also zero attnT.
// ---------------------------------------------------------------------------
__global__ __launch_bounds__(256) void
kstats_kernel(const bf16_t* __restrict__ qkv, float* __restrict__ kmax,
              float* __restrict__ kinv, float* __restrict__ attnT) {
    const int oc = blockIdx.x;
    const int t = threadIdx.x, w = t >> 6, ln = t & 63;
    if (oc < 128) attnT[oc * 256 + t] = 0.f;

    const bf16_t* row = qkv + (size_t)(512 + oc) * NP;
    float v[16];
    bf8 x0 = *(const bf8*)&row[t * 8];
    bf8 x1 = *(const bf8*)&row[2048 + t * 8];
    #pragma unroll
    for (int j = 0; j < 8; ++j) { v[j] = (float)x0[j]; v[8 + j] = (float)x1[j]; }

    float m = v[0];
    #pragma unroll
    for (int j = 1; j < 16; ++j) m = fmaxf(m, v[j]);
    #pragma unroll
    for (int off = 32; off > 0; off >>= 1) m = fmaxf(m, __shfl_down(m, off));
    __shared__ float sR[4];
    __shared__ float sS[4];
    if (ln == 0) sR[w] = m;
    __syncthreads();
    m = fmaxf(fmaxf(sR[0], sR[1]), fmaxf(sR[2], sR[3]));

    float s = 0.f;
    #pragma unroll
    for (int j = 0; j < 16; ++j) s += __expf(v[j] - m);
    #pragma unroll
    for (int off = 32; off > 0; off >>= 1) s += __shfl_down(s, off);
    if (ln == 0) sS[w] = s;
    __syncthreads();
    if (t == 0) {
        kmax[oc] = m;
        kinv[oc] = 1.0f / (sS[0] + sS[1] + sS[2] + sS[3]);
    }
}

// ---------------------------------------------------------------------------
// E: attnT[h][d][c] += sum_p exp(k[c][p]-kmax[c]) * v[d][p], one batch.
// grid(8, 32) block 256.
// ---------------------------------------------------------------------------
__global__ __launch_bounds__(256) void
attn_kernel(const bf16_t* __restrict__ qkv, const float* __restrict__ kmax,
            float* __restrict__ attnT) {
    const int h = blockIdx.x, ks = blockIdx.y;
    const int t = threadIdx.x, w = t >> 6, ln = t & 63, quad = ln >> 4, l16 = ln & 15;

    const bf16_t* Kb = qkv + (size_t)(512 + h * 64) * NP;
    const bf16_t* Vb = qkv + (size_t)(1024 + h * 64) * NP;

    float km[4];
    #pragma unroll
    for (int mi = 0; mi < 4; ++mi) km[mi] = kmax[h * 64 + mi * 16 + l16];

    const int p0 = ks * 128 + w * 32 + quad * 8;
    bf8 af[4], bfr[4];
    #pragma unroll
    for (int mi = 0; mi < 4; ++mi) {
        bf8 kr = *(const bf8*)&Kb[(size_t)(mi * 16 + l16) * NP + p0];
        #pragma unroll
        for (int j = 0; j < 8; ++j)
            af[mi][j] = (__bf16)__expf((float)kr[j] - km[mi]);
    }
    #pragma unroll
    for (int ni = 0; ni < 4; ++ni)
        bfr[ni] = *(const bf8*)&Vb[(size_t)(ni * 16 + l16) * NP + p0];

    f32x4 acc[4][4] = {};
    #pragma unroll
    for (int mi = 0; mi < 4; ++mi)
        #pragma unroll
        for (int ni = 0; ni < 4; ++ni)
            acc[mi][ni] = __builtin_amdgcn_mfma_f32_16x16x32_bf16(
                af[mi], bfr[ni], acc[mi][ni], 0, 0, 0);

    __shared__ __align__(16) float sAcc[64][65];
    #pragma unroll
    for (int i = 0; i < 17; ++i) {
        int idx = t + i * 256;
        if (idx < 64 * 65) ((float*)sAcc)[idx] = 0.f;
    }
    __syncthreads();
    #pragma unroll
    for (int mi = 0; mi < 4; ++mi)
        #pragma unroll
        for (int ni = 0; ni < 4; ++ni)
            #pragma unroll
            for (int r = 0; r < 4; ++r)
                atomicAdd(&sAcc[mi * 16 + quad * 4 + r][ni * 16 + l16], acc[mi][ni][r]);
    __syncthreads();
    #pragma unroll
    for (int i = 0; i < 16; ++i) {
        int e = t + i * 256;              // e = d*64 + c
        int d = e >> 6, c = e & 63;
        atomicAdd(&attnT[h * 4096 + e], sAcc[c][d]);
    }
}

// ---------------------------------------------------------------------------
// F: q softmax over ch (*SCALE) then xoT[p][h*64+d] = qsm @ (attn*kinv).
// One batch. grid(32, 8) block 256. xoT aliases V rows.
// ---------------------------------------------------------------------------
__global__ __launch_bounds__(256) void
outgemm_kernel(const bf16_t* __restrict__ qkv, const float* __restrict__ attnT,
               const float* __restrict__ kinv, bf16_t* __restrict__ xoT) {
    const int pt = blockIdx.x, h = blockIdx.y;
    const int p0 = pt * 128;
    const int t = threadIdx.x, w = t >> 6, ln = t & 63, quad = ln >> 4, l16 = ln & 15;

    __shared__ __align__(16) __bf16 sQb[128][LDP];   // [p][c]
    __shared__ __align__(16) __bf16 sAt[64][LDP];    // [d][c]
    __shared__ float sMax[128], sInv[128];

    #pragma unroll
    for (int i = 0; i < 16; ++i) {
        int e = t + i * 256;             // d*64 + c
        int d = e >> 6, c = e & 63;
        sAt[d][c] = (__bf16)(attnT[h * 4096 + e] * kinv[h * 64 + c]);
    }
    #pragma unroll
    for (int i = 0; i < 32; ++i) {
        int e = t + i * 256;             // c*128 + p
        int c = e >> 7, p = e & 127;
        sQb[p][c] = qkv[(size_t)(h * 64 + c) * NP + p0 + p];
    }
    __syncthreads();
    if (t < 128) {
        float m = -1e30f;
        #pragma unroll
        for (int c = 0; c < 64; ++c) m = fmaxf(m, (float)sQb[t][c]);
        float s = 0.f;
        #pragma unroll
        for (int c = 0; c < 64; ++c) s += __expf((float)sQb[t][c] - m);
        sMax[t] = m;
        sInv[t] = QSCALE / s;
    }
    __syncthreads();
    #pragma unroll
    for (int i = 0; i < 32; ++i) {
        int e = t + i * 256;             // p*64 + c
        int p = e >> 6, c = e & 63;
        sQb[p][c] = (__bf16)(__expf((float)sQb[p][c] - sMax[p]) * sInv[p]);
    }
    __syncthreads();

    f32x4 acc[2][4] = {};
    #pragma unroll
    for (int ksp = 0; ksp < 2; ++ksp) {
        const int kk = ksp * 32;
        bf8 af[2], bfr[4];
        #pragma unroll
        for (int mi = 0; mi < 2; ++mi)
            af[mi] = *(const bf8*)&sQb[w * 32 + mi * 16 + l16][kk + quad * 8];
        #pragma unroll
        for (int ni = 0; ni < 4; ++ni)
            bfr[ni] = *(const bf8*)&sAt[ni * 16 + l16][kk + quad * 8];
        #pragma unroll
        for (int mi = 0; mi < 2; ++mi)
            #pragma unroll
            for (int ni = 0; ni < 4; ++ni)
                acc[mi][ni] = __builtin_amdgcn_mfma_f32_16x16x32_bf16(
                    af[mi], bfr[ni], acc[mi][ni], 0, 0, 0);
    }
    #pragma unroll
    for (int mi = 0; mi < 2; ++mi)
        #pragma unroll
        for (int ni = 0; ni < 4; ++ni)
            #pragma unroll
            for (int r = 0; r < 4; ++r) {
                int p = p0 + w * 32 + mi * 16 + quad * 4 + r;
                int dg = h * 64 + ni * 16 + l16;
                xoT[(size_t)p * NC + dg] = (__bf16)acc[mi][ni][r];
            }
}

// ---------------------------------------------------------------------------
// G: FFN GEMM, one batch. grid(32, 4) block 256.
// ---------------------------------------------------------------------------
__global__ __launch_bounds__(256) void
gemm_ffn_kernel(const bf16_t* __restrict__ A, bf16_t* __restrict__ qkv,
                const bf16_t* __restrict__ bias) {
    const int bn = blockIdx.x, bm = blockIdx.y;
    const int t = threadIdx.x;
    const int w = t >> 6, ln = t & 63, quad = ln >> 4, l16 = ln & 15;
    const int wm = w >> 1, wn = w & 1;

    __shared__ __align__(16) __bf16 sA[128][LDP];
    __shared__ __align__(16) __bf16 sB[128][LDP];

    f32x4 acc[4][4] = {};
    const bf16_t* Abase = A + (size_t)(bm * 128) * NC;
    const bf16_t* Bbase = qkv + (size_t)1024 * NP + (size_t)(bn * 128) * NC;

    for (int kt = 0; kt < 8; ++kt) {
        const int k0 = kt * 64;
        #pragma unroll
        for (int i = 0; i < 8; ++i) {
            int idx = t + i * 256;
            int r = idx >> 4;
            int c4 = (idx & 15) * 4;
            *(ushort4*)&sA[r][c4] = *(const ushort4*)&Abase[(size_t)r * NC + k0 + c4];
            *(ushort4*)&sB[r][c4] = *(const ushort4*)&Bbase[(size_t)r * NC + k0 + c4];
        }
        __syncthreads();
        #pragma unroll
        for (int ks = 0; ks < 2; ++ks) {
            const int kk = ks * 32;
            bf8 af[4], bfr[4];
            #pragma unroll
            for (int mi = 0; mi < 4; ++mi)
                af[mi] = *(const bf8*)&sA[wm * 64 + mi * 16 + l16][kk + quad * 8];
            #pragma unroll
            for (int ni = 0; ni < 4; ++ni)
                bfr[ni] = *(const bf8*)&sB[wn * 64 + ni * 16 + l16][kk + quad * 8];
            #pragma unroll
            for (int mi = 0; mi < 4; ++mi)
                #pragma unroll
                for (int ni = 0; ni < 4; ++ni)
                    acc[mi][ni] = __builtin_amdgcn_mfma_f32_16x16x32_bf16(
                        af[mi], bfr[ni], acc[mi][ni], 0, 0, 0);
        }
        __syncthreads();
    }

    #pragma unroll
    for (int mi = 0; mi < 4; ++mi) {
        #pragma unroll
        for (int ni = 0; ni < 4; ++ni) {
            const int col = bn * 128 + wn * 64 + ni * 16 + l16;
            #pragma unroll
            for (int r = 0; r < 4; ++r) {
                const int row = bm * 128 + wm * 64 + mi * 16 + quad * 4 + r;
                float v = acc[mi][ni][r] + (float)bias[row];
                qkv[(size_t)row * NP + col] = (__bf16)v;
            }
        }
    }
}

// ---------------------------------------------------------------------------
// H1: invn2[p] = 1/||y[:,p]||, one batch. grid(32) block 256.
// ---------------------------------------------------------------------------
__global__ __launch_bounds__(256) void
ffnnorm_kernel(const bf16_t* __restrict__ qkv, float* __restrict__ invn2) {
    const int p0 = blockIdx.x * 128;
    const int t = threadIdx.x;
    const int p = p0 + (t & 127);
    const int obase = (t >> 7) * 256;
    float s = 0.f;
    for (int o = 0; o < 256; ++o) {
        float v = (float)qkv[(size_t)(obase + o) * NP + p];
        s += v * v;
    }
    __shared__ float sS[256];
    sS[t] = s;
    __syncthreads();
    if (t < 128)
        invn2[p0 + t] = 1.0f / fmaxf(sqrtf(sS[t] + sS[t + 128]), 1e-12f);
}

// ---------------------------------------------------------------------------
// H2: out = y*invn2*g2*sqrtC + x, one batch. FP32 OUTPUT; residual read from
// the raw x buffer in its native dtype. grid(1024) block 256, 8 elems/thread.
// ---------------------------------------------------------------------------
__global__ __launch_bounds__(256) void
final_kernel(const bf16_t* __restrict__ qkv, const float* __restrict__ invn2,
             const bf16_t* __restrict__ g2, const void* __restrict__ x_raw,
             size_t xoff, float* __restrict__ outb,
             const void* __restrict__ gref) {
    const bool isf32 = (((const unsigned short*)gref)[0] != 0x3F80u);
    int idx = blockIdx.x * 256 + threadIdx.x;      // [0, 262144)
    int o = idx >> 9;
    int p8 = (idx & 511) * 8;
    bf8 y = *(const bf8*)&qkv[(size_t)o * NP + p8];
    float gv = (float)g2[o] * SQRTC;

    float res[8];
    if (isf32) {
        const float* xb = (const float*)x_raw + xoff;
        float4 a = *(const float4*)&xb[(size_t)o * NP + p8];
        float4 b2 = *(const float4*)&xb[(size_t)o * NP + p8 + 4];
        res[0] = a.x;  res[1] = a.y;  res[2] = a.z;  res[3] = a.w;
        res[4] = b2.x; res[5] = b2.y; res[6] = b2.z; res[7] = b2.w;
    } else {
        const bf16_t* xb = (const bf16_t*)x_raw + xoff;
        bf8 xv = *(const bf8*)&xb[(size_t)o * NP + p8];
        #pragma unroll
        for (int j = 0; j < 8; ++j) res[j] = (float)xv[j];
    }

    float4 r0, r1;
    r0.x = (float)y[0] * invn2[p8 + 0] * gv + res[0];
    r0.y = (float)y[1] * invn2[p8 + 1] * gv + res[1];
    r0.z = (float)y[2] * invn2[p8 + 2] * gv + res[2];
    r0.w = (float)y[3] * invn2[p8 + 3] * gv + res[3];
    r1.x = (float)y[4] * invn2[p8 + 4] * gv + res[4];
    r1.y = (float)y[5] * invn2[p8 + 5] * gv + res[5];
    r1.z = (float)y[6] * invn2[p8 + 6] * gv + res[6];
    r1.w = (float)y[7] * invn2[p8 + 7] * gv + res[7];
    *(float4*)&outb[(size_t)o * NP + p8] = r0;
    *(float4*)&outb[(size_t)o * NP + p8 + 4] = r1;
}

// ---------------------------------------------------------------------------
extern "C" void kernel_launch(void* const* d_in, const int* in_sizes, int n_in,
                              void* d_out, int out_size, void* d_ws, size_t ws_size,
                              hipStream_t stream) {
    const void* x_raw    = d_in[0];
    const void* g_raw    = d_in[1];
    const void* qkvw_raw = d_in[2];
    const void* ffnw_raw = d_in[3];
    const void* ffnb_raw = d_in[4];
    const void* ffng_raw = d_in[5];
    float* out = (float*)d_out;                       // reference output dtype: fp32

    // workspace: canonical bf16 copies + pipeline buffers, ~48.7 MB total
    bf16_t* xc    = (bf16_t*)d_ws;                    // 16,777,216 bf16 = 33.55 MB
    bf16_t* wq    = xc + (size_t)16777216;            // 786,432 bf16
    bf16_t* wf    = wq + 786432;                      // 262,144 bf16
    bf16_t* gc    = wf + 262144;                      // 512
    bf16_t* bc    = gc + 512;                         // 512
    bf16_t* g2c   = bc + 512;                         // 512
    bf16_t* qkvb  = g2c + 512;                        // 6,291,456 bf16 = 12.58 MB
    float*  attnT = (float*)(qkvb + (size_t)6291456); // 32768 f32
    float*  kmax  = attnT + 32768;                    // 512
    float*  kinv  = kmax + 512;                       // 512
    float*  invn2 = kinv + 512;                       // 4096

    // canonicalize inputs to bf16 (dtype sniffed from norm_g == ones)
    convert_kernel<<<dim3(16384), 256, 0, stream>>>(x_raw, xc, 16777216, g_raw);
    convert_kernel<<<dim3(768), 256, 0, stream>>>(qkvw_raw, wq, 786432, g_raw);
    convert_kernel<<<dim3(256), 256, 0, stream>>>(ffnw_raw, wf, 262144, g_raw);
    convert_kernel<<<dim3(1), 256, 0, stream>>>(g_raw, gc, 512, g_raw);
    convert_kernel<<<dim3(1), 256, 0, stream>>>(ffnb_raw, bc, 512, g_raw);
    convert_kernel<<<dim3(1), 256, 0, stream>>>(ffng_raw, g2c, 512, g_raw);

    for (int b = 0; b < 8; ++b) {
        const bf16_t* xb = xc + (size_t)b * NC * NP;
        gemm_qkv_kernel<<<dim3(32, 12), 256, 0, stream>>>(wq, gc, xb, qkvb);
        kstats_kernel<<<dim3(512), 256, 0, stream>>>(qkvb, kmax, kinv, attnT);
        attn_kernel<<<dim3(8, 32), 256, 0, stream>>>(qkvb, kmax, attnT);
        outgemm_kernel<<<dim3(32, 8), 256, 0, stream>>>(qkvb, attnT, kinv,
                                                        qkvb + (size_t)1024 * NP);
        gemm_ffn_kernel<<<dim3(32, 4), 256, 0, stream>>>(wf, qkvb, bc);
        ffnnorm_kernel<<<dim3(32), 256, 0, stream>>>(qkvb, invn2);
        final_kernel<<<dim3(1024), 256, 0, stream>>>(
            qkvb, invn2, g2c, x_raw, (size_t)b * NC * NP,
            out + (size_t)b * NC * NP, g_raw);
    }
}

// Round 6
// 655.436 us; speedup vs baseline: 1.5746x; 1.5746x over previous
//
#include <hip/hip_runtime.h>

// ---------------------------------------------------------------------------
// MultiHeadsLinearAttention  (B=8, C=512, HEADS=8, CH=64, H=W=64 -> N=4096)
// Inputs fp32, output fp32. Compute: bf16 MFMA, fp32 accumulation.
//
// All pipeline kernels batched over blockIdx.z (8 batches) -> 9 launches.
// Memory plan:
//   ws  (36.8 MB): q/y (8*512*4096 bf16, Q then overwritten by FFN output y),
//                  Wg, Wf (bf16 weights), attnT/kmax/kinv/invn2 (f32 stats)
//   d_out (64 MB): used as bf16 scratch for K+V per batch (kv[b] = 1024 rows),
//                  then xoT overwrites the dead K region after attn;
//                  final_kernel overwrites the whole buffer with fp32 output.
//
// Stages:
//  W : Wg = qkv_w * g -> bf16 ; Wf = ffn_w -> bf16
//  C : QKV GEMM qkv[o][p] = invx[p]*sum_c Wg[o][c]*x[c][p]  (x fp32 read +
//      cvt in staging; sumsq of fp32 x accumulated during staging -> invx)
//  D : k-softmax stats (kmax,kinv) per (b,channel) + zero attnT
//  E : attnT[b][h][d][c] += sum_p exp(k[c][p]-kmax)*v[d][p]   (MFMA)
//  F : q-softmax over c per token; xoT[b][p][hd] = qsm @ (attn*kinv)
//  G : FFN GEMM y[o][p] = ffn_b[o] + sum_c Wf[o][c]*xoT[p][c]
//  H1: invn2[p] = 1/||y[:,p]|| ;  H2: out = y*invn2*g2*sqrtC + x  (fp32)
//
// LDS tiles: row stride 88 bf16 (176 B) -> 16B-aligned rows (ds_read_b128
// legal) and 44-dword row step -> 2-way bank aliasing (free, m136).
// ---------------------------------------------------------------------------

typedef __bf16 bf16_t;
typedef __bf16 bf8 __attribute__((ext_vector_type(8)));
typedef float f32x4 __attribute__((ext_vector_type(4)));

#define NC 512
#define NP 4096
#define SQRTC 22.62741699796952f
#define QSCALE 0.125f
#define LDP 88
#define QSTRIDE  ((size_t)NC * NP)      // 2097152  per-batch q/y elems (ws)
#define KVSTRIDE ((size_t)1024 * NP)    // 4194304  per-batch kv elems (d_out)

__device__ inline unsigned short bfbits(__bf16 h) {
    return __builtin_bit_cast(unsigned short, h);
}

// ---------------------------------------------------------------------------
// W: weight convert fp32->bf16, optional per-column scale g. 4 elems/thread.
// ---------------------------------------------------------------------------
__global__ __launch_bounds__(256) void
wconv_kernel(const float* __restrict__ w, const float* __restrict__ g,
             bf16_t* __restrict__ out) {
    int i0 = (blockIdx.x * 256 + threadIdx.x) * 4;
    float4 wv = *(const float4*)&w[i0];
    if (g) {
        const float4 gv = *(const float4*)&g[i0 & 511];
        wv.x *= gv.x; wv.y *= gv.y; wv.z *= gv.z; wv.w *= gv.w;
    }
    ushort4 o;
    o.x = bfbits((__bf16)wv.x);
    o.y = bfbits((__bf16)wv.y);
    o.z = bfbits((__bf16)wv.z);
    o.w = bfbits((__bf16)wv.w);
    *(ushort4*)&out[i0] = o;
}

// ---------------------------------------------------------------------------
// C: QKV GEMM, z-batched. grid(32, 12, 8) block 256.
// A = Wg bf16 (g pre-folded); B = x fp32 [c][p] -> cvt+transpose into LDS;
// per-token fp32 sumsq accumulated during staging -> invx in epilogue.
// Rows <512 (Q) -> qout (ws); rows >=512 (K,V) -> kvout (d_out).
// ---------------------------------------------------------------------------
__global__ __launch_bounds__(256) void
gemm_qkv_kernel(const bf16_t* __restrict__ Wg, const float* __restrict__ x,
                bf16_t* __restrict__ qout, bf16_t* __restrict__ kvout) {
    const int bn = blockIdx.x, bm = blockIdx.y, b = blockIdx.z;
    const int t = threadIdx.x;
    const int w = t >> 6, ln = t & 63, quad = ln >> 4, l16 = ln & 15;
    const int wm = w >> 1, wn = w & 1;

    __shared__ __align__(16) __bf16 sA[128][LDP];
    __shared__ __align__(16) __bf16 sB[128][LDP];
    __shared__ float sSS[256];
    __shared__ float sInvN[128];

    f32x4 acc[4][4] = {};
    float ss = 0.f;

    const bf16_t* Abase = Wg + (size_t)(bm * 128) * NC;
    const float* xb = x + (size_t)b * QSTRIDE;
    const int p0 = bn * 128;

    for (int kt = 0; kt < 8; ++kt) {
        const int k0 = kt * 64;
        #pragma unroll
        for (int i = 0; i < 8; ++i) {
            int idx = t + i * 256;            // < 2048
            int r = idx >> 4;
            int c4 = (idx & 15) * 4;
            *(ushort4*)&sA[r][c4] = *(const ushort4*)&Abase[(size_t)r * NC + k0 + c4];
        }
        #pragma unroll
        for (int i = 0; i < 8; ++i) {
            int idx = t + i * 256;            // < 2048
            int pp = idx & 127;               // constant per thread
            int c0 = (idx >> 7) * 4;
            const float* xs = &xb[(size_t)(k0 + c0) * NP + p0 + pp];
            float v0 = xs[0];
            float v1 = xs[NP];
            float v2 = xs[2 * NP];
            float v3 = xs[3 * NP];
            ss += v0 * v0 + v1 * v1 + v2 * v2 + v3 * v3;
            ushort4 u;
            u.x = bfbits((__bf16)v0);
            u.y = bfbits((__bf16)v1);
            u.z = bfbits((__bf16)v2);
            u.w = bfbits((__bf16)v3);
            *(ushort4*)&sB[pp][c0] = u;
        }
        __syncthreads();
        #pragma unroll
        for (int ks = 0; ks < 2; ++ks) {
            const int kk = ks * 32;
            bf8 af[4], bfr[4];
            #pragma unroll
            for (int mi = 0; mi < 4; ++mi)
                af[mi] = *(const bf8*)&sA[wm * 64 + mi * 16 + l16][kk + quad * 8];
            #pragma unroll
            for (int ni = 0; ni < 4; ++ni)
                bfr[ni] = *(const bf8*)&sB[wn * 64 + ni * 16 + l16][kk + quad * 8];
            #pragma unroll
            for (int mi = 0; mi < 4; ++mi)
                #pragma unroll
                for (int ni = 0; ni < 4; ++ni)
                    acc[mi][ni] = __builtin_amdgcn_mfma_f32_16x16x32_bf16(
                        af[mi], bfr[ni], acc[mi][ni], 0, 0, 0);
        }
        __syncthreads();
    }

    // threads t and t+128 hold complementary halves of column (t&127)'s sumsq
    sSS[t] = ss;
    __syncthreads();
    if (t < 128)
        sInvN[t] = SQRTC / fmaxf(sqrtf(sSS[t] + sSS[t + 128]), 1e-12f);
    __syncthreads();

    bf16_t* qb = qout + (size_t)b * QSTRIDE;
    bf16_t* kvb = kvout + (size_t)b * KVSTRIDE;
    #pragma unroll
    for (int ni = 0; ni < 4; ++ni) {
        const int colL = wn * 64 + ni * 16 + l16;
        const float sc = sInvN[colL];
        #pragma unroll
        for (int mi = 0; mi < 4; ++mi) {
            #pragma unroll
            for (int r = 0; r < 4; ++r) {
                const int row = bm * 128 + wm * 64 + mi * 16 + quad * 4 + r;
                const __bf16 val = (__bf16)(acc[mi][ni][r] * sc);
                if (row < 512)
                    qb[(size_t)row * NP + p0 + colL] = val;
                else
                    kvb[(size_t)(row - 512) * NP + p0 + colL] = val;
            }
        }
    }
}

// ---------------------------------------------------------------------------
// D: k-softmax stats per (b, channel) row. grid(512, 8) block 256.
// K = kv rows [0,512). Blocks oc<128 also zero this batch's attnT slice.
// ---------------------------------------------------------------------------
__global__ __launch_bounds__(256) void
kstats_kernel(const bf16_t* __restrict__ kv, float* __restrict__ kmax,
              float* __restrict__ kinv, float* __restrict__ attnT) {
    const int oc = blockIdx.x, b = blockIdx.y;
    const int t = threadIdx.x, w = t >> 6, ln = t & 63;
    if (oc < 128) attnT[b * 32768 + oc * 256 + t] = 0.f;

    const bf16_t* row = kv + (size_t)b * KVSTRIDE + (size_t)oc * NP;
    float v[16];
    bf8 x0 = *(const bf8*)&row[t * 8];
    bf8 x1 = *(const bf8*)&row[2048 + t * 8];
    #pragma unroll
    for (int j = 0; j < 8; ++j) { v[j] = (float)x0[j]; v[8 + j] = (float)x1[j]; }

    float m = v[0];
    #pragma unroll
    for (int j = 1; j < 16; ++j) m = fmaxf(m, v[j]);
    #pragma unroll
    for (int off = 32; off > 0; off >>= 1) m = fmaxf(m, __shfl_down(m, off));
    __shared__ float sR[4];
    __shared__ float sS[4];
    if (ln == 0) sR[w] = m;
    __syncthreads();
    m = fmaxf(fmaxf(sR[0], sR[1]), fmaxf(sR[2], sR[3]));

    float s = 0.f;
    #pragma unroll
    for (int j = 0; j < 16; ++j) s += __expf(v[j] - m);
    #pragma unroll
    for (int off = 32; off > 0; off >>= 1) s += __shfl_down(s, off);
    if (ln == 0) sS[w] = s;
    __syncthreads();
    if (t == 0) {
        kmax[b * 512 + oc] = m;
        kinv[b * 512 + oc] = 1.0f / (sS[0] + sS[1] + sS[2] + sS[3]);
    }
}

// ---------------------------------------------------------------------------
// E: attnT[b][h][d][c] += sum_p exp(k[c][p]-kmax[c]) * v[d][p].
// grid(8, 32, 8) block 256.
// ---------------------------------------------------------------------------
__global__ __launch_bounds__(256) void
attn_kernel(const bf16_t* __restrict__ kv, const float* __restrict__ kmax,
            float* __restrict__ attnT) {
    const int h = blockIdx.x, ks = blockIdx.y, b = blockIdx.z;
    const int t = threadIdx.x, w = t >> 6, ln = t & 63, quad = ln >> 4, l16 = ln & 15;

    const bf16_t* Kb = kv + (size_t)b * KVSTRIDE + (size_t)(h * 64) * NP;
    const bf16_t* Vb = kv + (size_t)b * KVSTRIDE + (size_t)(512 + h * 64) * NP;

    float km[4];
    #pragma unroll
    for (int mi = 0; mi < 4; ++mi) km[mi] = kmax[b * 512 + h * 64 + mi * 16 + l16];

    const int p0 = ks * 128 + w * 32 + quad * 8;
    bf8 af[4], bfr[4];
    #pragma unroll
    for (int mi = 0; mi < 4; ++mi) {
        bf8 kr = *(const bf8*)&Kb[(size_t)(mi * 16 + l16) * NP + p0];
        #pragma unroll
        for (int j = 0; j < 8; ++j)
            af[mi][j] = (__bf16)__expf((float)kr[j] - km[mi]);
    }
    #pragma unroll
    for (int ni = 0; ni < 4; ++ni)
        bfr[ni] = *(const bf8*)&Vb[(size_t)(ni * 16 + l16) * NP + p0];

    f32x4 acc[4][4] = {};
    #pragma unroll
    for (int mi = 0; mi < 4; ++mi)
        #pragma unroll
        for (int ni = 0; ni < 4; ++ni)
            acc[mi][ni] = __builtin_amdgcn_mfma_f32_16x16x32_bf16(
                af[mi], bfr[ni], acc[mi][ni], 0, 0, 0);

    __shared__ __align__(16) float sAcc[64][65];
    #pragma unroll
    for (int i = 0; i < 17; ++i) {
        int idx = t + i * 256;
        if (idx < 64 * 65) ((float*)sAcc)[idx] = 0.f;
    }
    __syncthreads();
    #pragma unroll
    for (int mi = 0; mi < 4; ++mi)
        #pragma unroll
        for (int ni = 0; ni < 4; ++ni)
            #pragma unroll
            for (int r = 0; r < 4; ++r)
                atomicAdd(&sAcc[mi * 16 + quad * 4 + r][ni * 16 + l16], acc[mi][ni][r]);
    __syncthreads();
    #pragma unroll
    for (int i = 0; i < 16; ++i) {
        int e = t + i * 256;              // e = d*64 + c
        int d = e >> 6, c = e & 63;
        atomicAdd(&attnT[b * 32768 + h * 4096 + e], sAcc[c][d]);
    }
}

// ---------------------------------------------------------------------------
// F: q softmax over ch (*SCALE) then xoT[p][h*64+d] = qsm @ (attn*kinv).
// grid(32, 8, 8) block 256. xoT overwrites dead K region of d_out.
// ---------------------------------------------------------------------------
__global__ __launch_bounds__(256) void
outgemm_kernel(const bf16_t* __restrict__ q, const float* __restrict__ attnT,
               const float* __restrict__ kinv, bf16_t* __restrict__ xoT) {
    const int pt = blockIdx.x, h = blockIdx.y, b = blockIdx.z;
    const int p0 = pt * 128;
    const int t = threadIdx.x, w = t >> 6, ln = t & 63, quad = ln >> 4, l16 = ln & 15;

    __shared__ __align__(16) __bf16 sQb[128][LDP];   // [p][c]
    __shared__ __align__(16) __bf16 sAt[64][LDP];    // [d][c]
    __shared__ float sMax[128], sInv[128];

    const bf16_t* qb = q + (size_t)b * QSTRIDE;
    #pragma unroll
    for (int i = 0; i < 16; ++i) {
        int e = t + i * 256;             // d*64 + c
        int d = e >> 6, c = e & 63;
        sAt[d][c] = (__bf16)(attnT[b * 32768 + h * 4096 + e] * kinv[b * 512 + h * 64 + c]);
    }
    #pragma unroll
    for (int i = 0; i < 32; ++i) {
        int e = t + i * 256;             // c*128 + p
        int c = e >> 7, p = e & 127;
        sQb[p][c] = qb[(size_t)(h * 64 + c) * NP + p0 + p];
    }
    __syncthreads();
    if (t < 128) {
        float m = -1e30f;
        #pragma unroll
        for (int c = 0; c < 64; ++c) m = fmaxf(m, (float)sQb[t][c]);
        float s = 0.f;
        #pragma unroll
        for (int c = 0; c < 64; ++c) s += __expf((float)sQb[t][c] - m);
        sMax[t] = m;
        sInv[t] = QSCALE / s;
    }
    __syncthreads();
    #pragma unroll
    for (int i = 0; i < 32; ++i) {
        int e = t + i * 256;             // p*64 + c
        int p = e >> 6, c = e & 63;
        sQb[p][c] = (__bf16)(__expf((float)sQb[p][c] - sMax[p]) * sInv[p]);
    }
    __syncthreads();

    f32x4 acc[2][4] = {};
    #pragma unroll
    for (int ksp = 0; ksp < 2; ++ksp) {
        const int kk = ksp * 32;
        bf8 af[2], bfr[4];
        #pragma unroll
        for (int mi = 0; mi < 2; ++mi)
            af[mi] = *(const bf8*)&sQb[w * 32 + mi * 16 + l16][kk + quad * 8];
        #pragma unroll
        for (int ni = 0; ni < 4; ++ni)
            bfr[ni] = *(const bf8*)&sAt[ni * 16 + l16][kk + quad * 8];
        #pragma unroll
        for (int mi = 0; mi < 2; ++mi)
            #pragma unroll
            for (int ni = 0; ni < 4; ++ni)
                acc[mi][ni] = __builtin_amdgcn_mfma_f32_16x16x32_bf16(
                    af[mi], bfr[ni], acc[mi][ni], 0, 0, 0);
    }
    bf16_t* xob = xoT + (size_t)b * KVSTRIDE;
    #pragma unroll
    for (int mi = 0; mi < 2; ++mi)
        #pragma unroll
        for (int ni = 0; ni < 4; ++ni)
            #pragma unroll
            for (int r = 0; r < 4; ++r) {
                int p = p0 + w * 32 + mi * 16 + quad * 4 + r;
                int dg = h * 64 + ni * 16 + l16;
                xob[(size_t)p * NC + dg] = (__bf16)acc[mi][ni][r];
            }
}

// ---------------------------------------------------------------------------
// G: FFN GEMM. grid(32, 4, 8) block 256.
// y[o][p] = ffn_b[o] + sum_c Wf[o][c]*xoT[p][c]; y overwrites dead Q (ws).
// ---------------------------------------------------------------------------
__global__ __launch_bounds__(256) void
gemm_ffn_kernel(const bf16_t* __restrict__ A, const bf16_t* __restrict__ xoT,
                const float* __restrict__ bias, bf16_t* __restrict__ y) {
    const int bn = blockIdx.x, bm = blockIdx.y, b = blockIdx.z;
    const int t = threadIdx.x;
    const int w = t >> 6, ln = t & 63, quad = ln >> 4, l16 = ln & 15;
    const int wm = w >> 1, wn = w & 1;

    __shared__ __align__(16) __bf16 sA[128][LDP];
    __shared__ __align__(16) __bf16 sB[128][LDP];

    f32x4 acc[4][4] = {};
    const bf16_t* Abase = A + (size_t)(bm * 128) * NC;
    const bf16_t* Bbase = xoT + (size_t)b * KVSTRIDE + (size_t)(bn * 128) * NC;

    for (int kt = 0; kt < 8; ++kt) {
        const int k0 = kt * 64;
        #pragma unroll
        for (int i = 0; i < 8; ++i) {
            int idx = t + i * 256;
            int r = idx >> 4;
            int c4 = (idx & 15) * 4;
            *(ushort4*)&sA[r][c4] = *(const ushort4*)&Abase[(size_t)r * NC + k0 + c4];
            *(ushort4*)&sB[r][c4] = *(const ushort4*)&Bbase[(size_t)r * NC + k0 + c4];
        }
        __syncthreads();
        #pragma unroll
        for (int ks = 0; ks < 2; ++ks) {
            const int kk = ks * 32;
            bf8 af[4], bfr[4];
            #pragma unroll
            for (int mi = 0; mi < 4; ++mi)
                af[mi] = *(const bf8*)&sA[wm * 64 + mi * 16 + l16][kk + quad * 8];
            #pragma unroll
            for (int ni = 0; ni < 4; ++ni)
                bfr[ni] = *(const bf8*)&sB[wn * 64 + ni * 16 + l16][kk + quad * 8];
            #pragma unroll
            for (int mi = 0; mi < 4; ++mi)
                #pragma unroll
                for (int ni = 0; ni < 4; ++ni)
                    acc[mi][ni] = __builtin_amdgcn_mfma_f32_16x16x32_bf16(
                        af[mi], bfr[ni], acc[mi][ni], 0, 0, 0);
        }
        __syncthreads();
    }

    bf16_t* yb = y + (size_t)b * QSTRIDE;
    #pragma unroll
    for (int mi = 0; mi < 4; ++mi) {
        #pragma unroll
        for (int ni = 0; ni < 4; ++ni) {
            const int col = bn * 128 + wn * 64 + ni * 16 + l16;
            #pragma unroll
            for (int r = 0; r < 4; ++r) {
                const int row = bm * 128 + wm * 64 + mi * 16 + quad * 4 + r;
                float v = acc[mi][ni][r] + bias[row];
                yb[(size_t)row * NP + col] = (__bf16)v;
            }
        }
    }
}

// ---------------------------------------------------------------------------
// H1: invn2[b][p] = 1/||y[:,p]||. grid(32, 8) block 256.
// ---------------------------------------------------------------------------
__global__ __launch_bounds__(256) void
ffnnorm_kernel(const bf16_t* __restrict__ y, float* __restrict__ invn2) {
    const int p0 = blockIdx.x * 128, b = blockIdx.y;
    const int t = threadIdx.x;
    const int p = p0 + (t & 127);
    const int obase = (t >> 7) * 256;
    const bf16_t* yb = y + (size_t)b * QSTRIDE;
    float s = 0.f;
    for (int o = 0; o < 256; ++o) {
        float v = (float)yb[(size_t)(obase + o) * NP + p];
        s += v * v;
    }
    __shared__ float sS[256];
    sS[t] = s;
    __syncthreads();
    if (t < 128)
        invn2[b * NP + p0 + t] = 1.0f / fmaxf(sqrtf(sS[t] + sS[t + 128]), 1e-12f);
}

// ---------------------------------------------------------------------------
// H2: out = y*invn2*g2*sqrtC + x (fp32 out). grid(1024, 8) block 256.
// ---------------------------------------------------------------------------
__global__ __launch_bounds__(256) void
final_kernel(const bf16_t* __restrict__ y, const float* __restrict__ invn2,
             const float* __restrict__ g2, const float* __restrict__ x,
             float* __restrict__ out) {
    const int b = blockIdx.y;
    int idx = blockIdx.x * 256 + threadIdx.x;      // [0, 262144)
    int o = idx >> 9;
    int p8 = (idx & 511) * 8;
    const bf16_t* yb = y + (size_t)b * QSTRIDE;
    const float* xb = x + (size_t)b * QSTRIDE;
    float* outb = out + (size_t)b * QSTRIDE;
    const float* inb = invn2 + (size_t)b * NP;

    bf8 yv = *(const bf8*)&yb[(size_t)o * NP + p8];
    float gv = g2[o] * SQRTC;
    float4 a = *(const float4*)&xb[(size_t)o * NP + p8];
    float4 b2 = *(const float4*)&xb[(size_t)o * NP + p8 + 4];

    float4 r0, r1;
    r0.x = (float)yv[0] * inb[p8 + 0] * gv + a.x;
    r0.y = (float)yv[1] * inb[p8 + 1] * gv + a.y;
    r0.z = (float)yv[2] * inb[p8 + 2] * gv + a.z;
    r0.w = (float)yv[3] * inb[p8 + 3] * gv + a.w;
    r1.x = (float)yv[4] * inb[p8 + 4] * gv + b2.x;
    r1.y = (float)yv[5] * inb[p8 + 5] * gv + b2.y;
    r1.z = (float)yv[6] * inb[p8 + 6] * gv + b2.z;
    r1.w = (float)yv[7] * inb[p8 + 7] * gv + b2.w;
    *(float4*)&outb[(size_t)o * NP + p8] = r0;
    *(float4*)&outb[(size_t)o * NP + p8 + 4] = r1;
}

// ---------------------------------------------------------------------------
extern "C" void kernel_launch(void* const* d_in, const int* in_sizes, int n_in,
                              void* d_out, int out_size, void* d_ws, size_t ws_size,
                              hipStream_t stream) {
    const float* x     = (const float*)d_in[0];
    const float* g     = (const float*)d_in[1];
    const float* qkv_w = (const float*)d_in[2];
    const float* ffn_w = (const float*)d_in[3];
    const float* ffn_b = (const float*)d_in[4];
    const float* ffn_g = (const float*)d_in[5];
    float* out = (float*)d_out;
    bf16_t* kv = (bf16_t*)d_out;     // 8 * 1024*4096 bf16 = 64 MB (K,V then xoT)

    // workspace (~36.8 MB)
    bf16_t* q     = (bf16_t*)d_ws;                   // 8*512*4096 bf16 (Q, then y)
    bf16_t* Wg    = q + 8 * QSTRIDE;                 // 786432 bf16
    bf16_t* Wf    = Wg + 786432;                     // 262144 bf16
    float*  attnT = (float*)(Wf + 262144);           // 8*32768 f32
    float*  kmax  = attnT + 8 * 32768;               // 8*512 f32
    float*  kinv  = kmax + 8 * 512;                  // 8*512 f32
    float*  invn2 = kinv + 8 * 512;                  // 8*4096 f32

    wconv_kernel<<<dim3(768), 256, 0, stream>>>(qkv_w, g, Wg);
    wconv_kernel<<<dim3(256), 256, 0, stream>>>(ffn_w, nullptr, Wf);

    gemm_qkv_kernel<<<dim3(32, 12, 8), 256, 0, stream>>>(Wg, x, q, kv);
    kstats_kernel<<<dim3(512, 8), 256, 0, stream>>>(kv, kmax, kinv, attnT);
    attn_kernel<<<dim3(8, 32, 8), 256, 0, stream>>>(kv, kmax, attnT);
    outgemm_kernel<<<dim3(32, 8, 8), 256, 0, stream>>>(q, attnT, kinv, kv);
    gemm_ffn_kernel<<<dim3(32, 4, 8), 256, 0, stream>>>(Wf, kv, ffn_b, q);
    ffnnorm_kernel<<<dim3(32, 8), 256, 0, stream>>>(q, invn2);
    final_kernel<<<dim3(1024, 8), 256, 0, stream>>>(q, invn2, ffn_g, x, out);
}

// Round 8
// 598.725 us; speedup vs baseline: 1.7238x; 1.0947x over previous
//
#include <hip/hip_runtime.h>

// ---------------------------------------------------------------------------
// MultiHeadsLinearAttention  (B=8, C=512, HEADS=8, CH=64, H=W=64 -> N=4096)
// Inputs fp32, output fp32. Compute: bf16 MFMA, fp32 accumulation.
//
// Stages:
//  W : Wg = qkv_w * g -> bf16 ; Wf = ffn_w -> bf16
//  T : per-token invx over fp32 x; xnT[p][c] = x*invx*sqrtC  (bf16, k-contig)
//      chunked 2 batches at a time, serialized with C-chunks
//  C : QKV GEMM (128x128 tile, BK=64, both operands k-contiguous,
//      synchronous ushort4->LDS staging): rows<512 -> Q (ws), else K,V (d_out)
//  D : k-softmax stats (kmax,kinv) + zero attnT
//  E : attnT[b][h][d][c] += sum_p exp(k[c][p]-kmax)*v[d][p]   (MFMA)
//  F : q-softmax per token; xoT[b][p][hd] = qsm @ (attn*kinv) (overwrites K)
//  G : FFN GEMM y = ffn_b + Wf @ xoT  (overwrites Q)
//  H1: invn2 = 1/||y||  ;  H2: out = y*invn2*g2*sqrtC + x  (fp32)
//
// NOTE (round-7 lesson): global_load_lds + XOR-swizzle staging produced a
// deterministic post-graph-replay divergence (first call correct, later calls
// identically wrong). Reverted to the synchronous staging that survived full
// graph timing in rounds 5/6; structural wins (k-contiguous operands via
// hoisted transpose, batched launches) retained.
// LDS tiles: row stride 88 bf16 (176 B) -> every row 16B-aligned for
// ds_read_b128; 44-dword row step -> 2-way bank aliasing (free, m136).
// ---------------------------------------------------------------------------

typedef __bf16 bf16_t;
typedef __bf16 bf8 __attribute__((ext_vector_type(8)));
typedef float f32x4 __attribute__((ext_vector_type(4)));

#define NC 512
#define NP 4096
#define SQRTC 22.62741699796952f
#define QSCALE 0.125f
#define LDP 88
#define QSTRIDE  ((size_t)NC * NP)      // 2097152  per-batch 512-row elems
#define KVSTRIDE ((size_t)1024 * NP)    // 4194304  per-batch kv elems (d_out)

__device__ inline unsigned short bfbits(__bf16 h) {
    return __builtin_bit_cast(unsigned short, h);
}

// ---------------------------------------------------------------------------
// W: weight convert fp32->bf16, optional per-column scale g. 4 elems/thread.
// ---------------------------------------------------------------------------
__global__ __launch_bounds__(256) void
wconv_kernel(const float* __restrict__ w, const float* __restrict__ g,
             bf16_t* __restrict__ out) {
    int i0 = (blockIdx.x * 256 + threadIdx.x) * 4;
    float4 wv = *(const float4*)&w[i0];
    if (g) {
        const float4 gv = *(const float4*)&g[i0 & 511];
        wv.x *= gv.x; wv.y *= gv.y; wv.z *= gv.z; wv.w *= gv.w;
    }
    ushort4 o;
    o.x = bfbits((__bf16)wv.x);
    o.y = bfbits((__bf16)wv.y);
    o.z = bfbits((__bf16)wv.z);
    o.w = bfbits((__bf16)wv.w);
    *(ushort4*)&out[i0] = o;
}

// ---------------------------------------------------------------------------
// T: norm + transpose, 2 batches per launch. grid(32, 2) block 256.
// xnT[p][c] = x[c][p] * (sqrtC / max(||x[:,p]||,1e-12))   bf16
// ---------------------------------------------------------------------------
__global__ __launch_bounds__(256) void
norm_transpose_kernel(const float* __restrict__ x, bf16_t* __restrict__ xnT) {
    const int bl = blockIdx.y;
    const int p0 = blockIdx.x * 128;
    const int t = threadIdx.x;
    const float* xb = x + (size_t)bl * QSTRIDE;
    bf16_t* ob = xnT + (size_t)bl * QSTRIDE;

    // pass 1: sumsq (threads t, t+128 split the c range of token p0+(t&127))
    const int pp = t & 127;
    const int ch = (t >> 7) * 256;
    float ss = 0.f;
    for (int c = 0; c < 256; ++c) {
        float v = xb[(size_t)(ch + c) * NP + p0 + pp];
        ss += v * v;
    }
    __shared__ float sS[256];
    __shared__ float sInv[128];
    sS[t] = ss;
    __syncthreads();
    if (t < 128)
        sInv[t] = SQRTC / fmaxf(sqrtf(sS[t] + sS[t + 128]), 1e-12f);
    __syncthreads();

    // pass 2: 32-c chunks through LDS transpose
    __shared__ __bf16 sT[32][136];
    for (int cc = 0; cc < 512; cc += 32) {
        #pragma unroll
        for (int j = 0; j < 16; ++j) {
            int e = t + j * 256;                 // 32c x 128p
            int cr = e >> 7, p = e & 127;
            sT[cr][p] = (__bf16)(xb[(size_t)(cc + cr) * NP + p0 + p] * sInv[p]);
        }
        __syncthreads();
        #pragma unroll
        for (int j = 0; j < 2; ++j) {
            int e = t + j * 256;                 // 512 chunks of 8 elems
            int p = e >> 2, c8 = (e & 3) * 8;
            bf8 v;
            #pragma unroll
            for (int q = 0; q < 8; ++q) v[q] = sT[c8 + q][p];
            *(bf8*)&ob[(size_t)(p0 + p) * NC + cc + c8] = v;
        }
        __syncthreads();
    }
}

// ---------------------------------------------------------------------------
// C: QKV GEMM. grid(32, 12, nb) block 256 (nb batches per launch).
// A = Wg [1536][512], B = xnT [p][c] (both k-contiguous bf16).
// 128x128 tile, BK=64, 4 waves of 64x64. Synchronous ushort4 staging.
// ---------------------------------------------------------------------------
__global__ __launch_bounds__(256) void
gemm_qkv_kernel(const bf16_t* __restrict__ Wg, const bf16_t* __restrict__ xnT,
                bf16_t* __restrict__ qout, bf16_t* __restrict__ kvout) {
    const int bn = blockIdx.x, bm = blockIdx.y, b = blockIdx.z;
    const int t = threadIdx.x;
    const int w = t >> 6, ln = t & 63, quad = ln >> 4, l16 = ln & 15;
    const int wm = w >> 1, wn = w & 1;

    __shared__ __align__(16) __bf16 sA[128][LDP];
    __shared__ __align__(16) __bf16 sB[128][LDP];

    f32x4 acc[4][4] = {};
    const bf16_t* Abase = Wg + (size_t)(bm * 128) * NC;
    const bf16_t* Bbase = xnT + (size_t)b * QSTRIDE + (size_t)(bn * 128) * NC;

    for (int kt = 0; kt < 8; ++kt) {
        const int k0 = kt * 64;
        #pragma unroll
        for (int i = 0; i < 8; ++i) {
            int idx = t + i * 256;            // < 2048
            int r = idx >> 4;
            int c4 = (idx & 15) * 4;
            *(ushort4*)&sA[r][c4] = *(const ushort4*)&Abase[(size_t)r * NC + k0 + c4];
            *(ushort4*)&sB[r][c4] = *(const ushort4*)&Bbase[(size_t)r * NC + k0 + c4];
        }
        __syncthreads();
        #pragma unroll
        for (int ks = 0; ks < 2; ++ks) {
            const int kk = ks * 32;
            bf8 af[4], bfr[4];
            #pragma unroll
            for (int mi = 0; mi < 4; ++mi)
                af[mi] = *(const bf8*)&sA[wm * 64 + mi * 16 + l16][kk + quad * 8];
            #pragma unroll
            for (int ni = 0; ni < 4; ++ni)
                bfr[ni] = *(const bf8*)&sB[wn * 64 + ni * 16 + l16][kk + quad * 8];
            #pragma unroll
            for (int mi = 0; mi < 4; ++mi)
                #pragma unroll
                for (int ni = 0; ni < 4; ++ni)
                    acc[mi][ni] = __builtin_amdgcn_mfma_f32_16x16x32_bf16(
                        af[mi], bfr[ni], acc[mi][ni], 0, 0, 0);
        }
        __syncthreads();
    }

    bf16_t* qb = qout + (size_t)b * QSTRIDE;
    bf16_t* kvb = kvout + (size_t)b * KVSTRIDE;
    const int p0 = bn * 128;
    #pragma unroll
    for (int ni = 0; ni < 4; ++ni) {
        const int colL = wn * 64 + ni * 16 + l16;
        #pragma unroll
        for (int mi = 0; mi < 4; ++mi) {
            #pragma unroll
            for (int r = 0; r < 4; ++r) {
                const int row = bm * 128 + wm * 64 + mi * 16 + quad * 4 + r;
                const __bf16 val = (__bf16)acc[mi][ni][r];
                if (row < 512)
                    qb[(size_t)row * NP + p0 + colL] = val;
                else
                    kvb[(size_t)(row - 512) * NP + p0 + colL] = val;
            }
        }
    }
}

// ---------------------------------------------------------------------------
// G: FFN GEMM. grid(32, 4, 8) block 256.
// A = Wf [512][512], B = xoT [p][c] (d_out K region), out y (+bias) -> ws.
// ---------------------------------------------------------------------------
__global__ __launch_bounds__(256) void
gemm_ffn_kernel(const bf16_t* __restrict__ Wf, const bf16_t* __restrict__ xoT,
                const float* __restrict__ bias, bf16_t* __restrict__ y) {
    const int bn = blockIdx.x, bm = blockIdx.y, b = blockIdx.z;
    const int t = threadIdx.x;
    const int w = t >> 6, ln = t & 63, quad = ln >> 4, l16 = ln & 15;
    const int wm = w >> 1, wn = w & 1;

    __shared__ __align__(16) __bf16 sA[128][LDP];
    __shared__ __align__(16) __bf16 sB[128][LDP];

    f32x4 acc[4][4] = {};
    const bf16_t* Abase = Wf + (size_t)(bm * 128) * NC;
    const bf16_t* Bbase = xoT + (size_t)b * KVSTRIDE + (size_t)(bn * 128) * NC;

    for (int kt = 0; kt < 8; ++kt) {
        const int k0 = kt * 64;
        #pragma unroll
        for (int i = 0; i < 8; ++i) {
            int idx = t + i * 256;
            int r = idx >> 4;
            int c4 = (idx & 15) * 4;
            *(ushort4*)&sA[r][c4] = *(const ushort4*)&Abase[(size_t)r * NC + k0 + c4];
            *(ushort4*)&sB[r][c4] = *(const ushort4*)&Bbase[(size_t)r * NC + k0 + c4];
        }
        __syncthreads();
        #pragma unroll
        for (int ks = 0; ks < 2; ++ks) {
            const int kk = ks * 32;
            bf8 af[4], bfr[4];
            #pragma unroll
            for (int mi = 0; mi < 4; ++mi)
                af[mi] = *(const bf8*)&sA[wm * 64 + mi * 16 + l16][kk + quad * 8];
            #pragma unroll
            for (int ni = 0; ni < 4; ++ni)
                bfr[ni] = *(const bf8*)&sB[wn * 64 + ni * 16 + l16][kk + quad * 8];
            #pragma unroll
            for (int mi = 0; mi < 4; ++mi)
                #pragma unroll
                for (int ni = 0; ni < 4; ++ni)
                    acc[mi][ni] = __builtin_amdgcn_mfma_f32_16x16x32_bf16(
                        af[mi], bfr[ni], acc[mi][ni], 0, 0, 0);
        }
        __syncthreads();
    }

    bf16_t* yb = y + (size_t)b * QSTRIDE;
    const int p0 = bn * 128;
    #pragma unroll
    for (int mi = 0; mi < 4; ++mi) {
        #pragma unroll
        for (int ni = 0; ni < 4; ++ni) {
            const int col = p0 + wn * 64 + ni * 16 + l16;
            #pragma unroll
            for (int r = 0; r < 4; ++r) {
                const int row = bm * 128 + wm * 64 + mi * 16 + quad * 4 + r;
                float v = acc[mi][ni][r] + bias[row];
                yb[(size_t)row * NP + col] = (__bf16)v;
            }
        }
    }
}

// ---------------------------------------------------------------------------
// D: k-softmax stats per (b, channel) row. grid(512, 8) block 256.
// ---------------------------------------------------------------------------
__global__ __launch_bounds__(256) void
kstats_kernel(const bf16_t* __restrict__ kv, float* __restrict__ kmax,
              float* __restrict__ kinv, float* __restrict__ attnT) {
    const int oc = blockIdx.x, b = blockIdx.y;
    const int t = threadIdx.x, w = t >> 6, ln = t & 63;
    if (oc < 128) attnT[b * 32768 + oc * 256 + t] = 0.f;

    const bf16_t* row = kv + (size_t)b * KVSTRIDE + (size_t)oc * NP;
    float v[16];
    bf8 x0 = *(const bf8*)&row[t * 8];
    bf8 x1 = *(const bf8*)&row[2048 + t * 8];
    #pragma unroll
    for (int j = 0; j < 8; ++j) { v[j] = (float)x0[j]; v[8 + j] = (float)x1[j]; }

    float m = v[0];
    #pragma unroll
    for (int j = 1; j < 16; ++j) m = fmaxf(m, v[j]);
    #pragma unroll
    for (int off = 32; off > 0; off >>= 1) m = fmaxf(m, __shfl_down(m, off));
    __shared__ float sR[4];
    __shared__ float sS[4];
    if (ln == 0) sR[w] = m;
    __syncthreads();
    m = fmaxf(fmaxf(sR[0], sR[1]), fmaxf(sR[2], sR[3]));

    float s = 0.f;
    #pragma unroll
    for (int j = 0; j < 16; ++j) s += __expf(v[j] - m);
    #pragma unroll
    for (int off = 32; off > 0; off >>= 1) s += __shfl_down(s, off);
    if (ln == 0) sS[w] = s;
    __syncthreads();
    if (t == 0) {
        kmax[b * 512 + oc] = m;
        kinv[b * 512 + oc] = 1.0f / (sS[0] + sS[1] + sS[2] + sS[3]);
    }
}

// ---------------------------------------------------------------------------
// E: attnT[b][h][d][c] += sum_p exp(k[c][p]-kmax[c]) * v[d][p].
// grid(8, 32, 8) block 256.
// ---------------------------------------------------------------------------
__global__ __launch_bounds__(256) void
attn_kernel(const bf16_t* __restrict__ kv, const float* __restrict__ kmax,
            float* __restrict__ attnT) {
    const int h = blockIdx.x, ks = blockIdx.y, b = blockIdx.z;
    const int t = threadIdx.x, w = t >> 6, ln = t & 63, quad = ln >> 4, l16 = ln & 15;

    const bf16_t* Kb = kv + (size_t)b * KVSTRIDE + (size_t)(h * 64) * NP;
    const bf16_t* Vb = kv + (size_t)b * KVSTRIDE + (size_t)(512 + h * 64) * NP;

    float km[4];
    #pragma unroll
    for (int mi = 0; mi < 4; ++mi) km[mi] = kmax[b * 512 + h * 64 + mi * 16 + l16];

    const int p0 = ks * 128 + w * 32 + quad * 8;
    bf8 af[4], bfr[4];
    #pragma unroll
    for (int mi = 0; mi < 4; ++mi) {
        bf8 kr = *(const bf8*)&Kb[(size_t)(mi * 16 + l16) * NP + p0];
        #pragma unroll
        for (int j = 0; j < 8; ++j)
            af[mi][j] = (__bf16)__expf((float)kr[j] - km[mi]);
    }
    #pragma unroll
    for (int ni = 0; ni < 4; ++ni)
        bfr[ni] = *(const bf8*)&Vb[(size_t)(ni * 16 + l16) * NP + p0];

    f32x4 acc[4][4] = {};
    #pragma unroll
    for (int mi = 0; mi < 4; ++mi)
        #pragma unroll
        for (int ni = 0; ni < 4; ++ni)
            acc[mi][ni] = __builtin_amdgcn_mfma_f32_16x16x32_bf16(
                af[mi], bfr[ni], acc[mi][ni], 0, 0, 0);

    __shared__ __align__(16) float sAcc[64][65];
    #pragma unroll
    for (int i = 0; i < 17; ++i) {
        int idx = t + i * 256;
        if (idx < 64 * 65) ((float*)sAcc)[idx] = 0.f;
    }
    __syncthreads();
    #pragma unroll
    for (int mi = 0; mi < 4; ++mi)
        #pragma unroll
        for (int ni = 0; ni < 4; ++ni)
            #pragma unroll
            for (int r = 0; r < 4; ++r)
                atomicAdd(&sAcc[mi * 16 + quad * 4 + r][ni * 16 + l16], acc[mi][ni][r]);
    __syncthreads();
    #pragma unroll
    for (int i = 0; i < 16; ++i) {
        int e = t + i * 256;              // e = d*64 + c
        int d = e >> 6, c = e & 63;
        atomicAdd(&attnT[b * 32768 + h * 4096 + e], sAcc[c][d]);
    }
}

// ---------------------------------------------------------------------------
// F: q softmax over ch (*SCALE) then xoT[p][h*64+d] = qsm @ (attn*kinv).
// grid(32, 8, 8) block 256. xoT overwrites dead K region of d_out.
// ---------------------------------------------------------------------------
__global__ __launch_bounds__(256) void
outgemm_kernel(const bf16_t* __restrict__ q, const float* __restrict__ attnT,
               const float* __restrict__ kinv, bf16_t* __restrict__ xoT) {
    const int pt = blockIdx.x, h = blockIdx.y, b = blockIdx.z;
    const int p0 = pt * 128;
    const int t = threadIdx.x, w = t >> 6, ln = t & 63, quad = ln >> 4, l16 = ln & 15;

    __shared__ __align__(16) __bf16 sQb[128][LDP];   // [p][c]
    __shared__ __align__(16) __bf16 sAt[64][LDP];    // [d][c]
    __shared__ float sMax[128], sInv[128];

    const bf16_t* qb = q + (size_t)b * QSTRIDE;
    #pragma unroll
    for (int i = 0; i < 16; ++i) {
        int e = t + i * 256;             // d*64 + c
        int d = e >> 6, c = e & 63;
        sAt[d][c] = (__bf16)(attnT[b * 32768 + h * 4096 + e] * kinv[b * 512 + h * 64 + c]);
    }
    #pragma unroll
    for (int i = 0; i < 32; ++i) {
        int e = t + i * 256;             // c*128 + p
        int c = e >> 7, p = e & 127;
        sQb[p][c] = qb[(size_t)(h * 64 + c) * NP + p0 + p];
    }
    __syncthreads();
    if (t < 128) {
        float m = -1e30f;
        #pragma unroll
        for (int c = 0; c < 64; ++c) m = fmaxf(m, (float)sQb[t][c]);
        float s = 0.f;
        #pragma unroll
        for (int c = 0; c < 64; ++c) s += __expf((float)sQb[t][c] - m);
        sMax[t] = m;
        sInv[t] = QSCALE / s;
    }
    __syncthreads();
    #pragma unroll
    for (int i = 0; i < 32; ++i) {
        int e = t + i * 256;             // p*64 + c
        int p = e >> 6, c = e & 63;
        sQb[p][c] = (__bf16)(__expf((float)sQb[p][c] - sMax[p]) * sInv[p]);
    }
    __syncthreads();

    f32x4 acc[2][4] = {};
    #pragma unroll
    for (int ksp = 0; ksp < 2; ++ksp) {
        const int kk = ksp * 32;
        bf8 af[2], bfr[4];
        #pragma unroll
        for (int mi = 0; mi < 2; ++mi)
            af[mi] = *(const bf8*)&sQb[w * 32 + mi * 16 + l16][kk + quad * 8];
        #pragma unroll
        for (int ni = 0; ni < 4; ++ni)
            bfr[ni] = *(const bf8*)&sAt[ni * 16 + l16][kk + quad * 8];
        #pragma unroll
        for (int mi = 0; mi < 2; ++mi)
            #pragma unroll
            for (int ni = 0; ni < 4; ++ni)
                acc[mi][ni] = __builtin_amdgcn_mfma_f32_16x16x32_bf16(
                    af[mi], bfr[ni], acc[mi][ni], 0, 0, 0);
    }
    bf16_t* xob = xoT + (size_t)b * KVSTRIDE;
    #pragma unroll
    for (int mi = 0; mi < 2; ++mi)
        #pragma unroll
        for (int ni = 0; ni < 4; ++ni)
            #pragma unroll
            for (int r = 0; r < 4; ++r) {
                int p = p0 + w * 32 + mi * 16 + quad * 4 + r;
                int dg = h * 64 + ni * 16 + l16;
                xob[(size_t)p * NC + dg] = (__bf16)acc[mi][ni][r];
            }
}

// ---------------------------------------------------------------------------
// H1: invn2[b][p] = 1/||y[:,p]||. grid(32, 8) block 256.
// ---------------------------------------------------------------------------
__global__ __launch_bounds__(256) void
ffnnorm_kernel(const bf16_t* __restrict__ y, float* __restrict__ invn2) {
    const int p0 = blockIdx.x * 128, b = blockIdx.y;
    const int t = threadIdx.x;
    const int p = p0 + (t & 127);
    const int obase = (t >> 7) * 256;
    const bf16_t* yb = y + (size_t)b * QSTRIDE;
    float s = 0.f;
    for (int o = 0; o < 256; ++o) {
        float v = (float)yb[(size_t)(obase + o) * NP + p];
        s += v * v;
    }
    __shared__ float sS[256];
    sS[t] = s;
    __syncthreads();
    if (t < 128)
        invn2[b * NP + p0 + t] = 1.0f / fmaxf(sqrtf(sS[t] + sS[t + 128]), 1e-12f);
}

// ---------------------------------------------------------------------------
// H2: out = y*invn2*g2*sqrtC + x (fp32 out). grid(1024, 8) block 256.
// ---------------------------------------------------------------------------
__global__ __launch_bounds__(256) void
final_kernel(const bf16_t* __restrict__ y, const float* __restrict__ invn2,
             const float* __restrict__ g2, const float* __restrict__ x,
             float* __restrict__ out) {
    const int b = blockIdx.y;
    int idx = blockIdx.x * 256 + threadIdx.x;      // [0, 262144)
    int o = idx >> 9;
    int p8 = (idx & 511) * 8;
    const bf16_t* yb = y + (size_t)b * QSTRIDE;
    const float* xb = x + (size_t)b * QSTRIDE;
    float* outb = out + (size_t)b * QSTRIDE;
    const float* inb = invn2 + (size_t)b * NP;

    bf8 yv = *(const bf8*)&yb[(size_t)o * NP + p8];
    float gv = g2[o] * SQRTC;
    float4 a = *(const float4*)&xb[(size_t)o * NP + p8];
    float4 b2 = *(const float4*)&xb[(size_t)o * NP + p8 + 4];

    float4 r0, r1;
    r0.x = (float)yv[0] * inb[p8 + 0] * gv + a.x;
    r0.y = (float)yv[1] * inb[p8 + 1] * gv + a.y;
    r0.z = (float)yv[2] * inb[p8 + 2] * gv + a.z;
    r0.w = (float)yv[3] * inb[p8 + 3] * gv + a.w;
    r1.x = (float)yv[4] * inb[p8 + 4] * gv + b2.x;
    r1.y = (float)yv[5] * inb[p8 + 5] * gv + b2.y;
    r1.z = (float)yv[6] * inb[p8 + 6] * gv + b2.z;
    r1.w = (float)yv[7] * inb[p8 + 7] * gv + b2.w;
    *(float4*)&outb[(size_t)o * NP + p8] = r0;
    *(float4*)&outb[(size_t)o * NP + p8 + 4] = r1;
}

// ---------------------------------------------------------------------------
extern "C" void kernel_launch(void* const* d_in, const int* in_sizes, int n_in,
                              void* d_out, int out_size, void* d_ws, size_t ws_size,
                              hipStream_t stream) {
    const float* x     = (const float*)d_in[0];
    const float* g     = (const float*)d_in[1];
    const float* qkv_w = (const float*)d_in[2];
    const float* ffn_w = (const float*)d_in[3];
    const float* ffn_b = (const float*)d_in[4];
    const float* ffn_g = (const float*)d_in[5];
    float* out = (float*)d_out;
    bf16_t* kv = (bf16_t*)d_out;     // 8*KVSTRIDE bf16 = 64 MiB (K,V then xoT)

    // workspace (~45.2 MB, within proven-safe budget)
    bf16_t* q     = (bf16_t*)d_ws;                   // 8*QSTRIDE bf16 (Q, then y)
    bf16_t* xnT2  = q + 8 * QSTRIDE;                 // 2*QSTRIDE bf16 (chunk)
    bf16_t* Wg    = xnT2 + 2 * QSTRIDE;              // 786432 bf16
    bf16_t* Wf    = Wg + 786432;                     // 262144 bf16
    float*  attnT = (float*)(Wf + 262144);           // 8*32768 f32
    float*  kmax  = attnT + 8 * 32768;               // 8*512 f32
    float*  kinv  = kmax + 8 * 512;                  // 8*512 f32
    float*  invn2 = kinv + 8 * 512;                  // 8*4096 f32

    wconv_kernel<<<dim3(768), 256, 0, stream>>>(qkv_w, g, Wg);
    wconv_kernel<<<dim3(256), 256, 0, stream>>>(ffn_w, nullptr, Wf);

    // chunked: normalize+transpose 2 batches, then their QKV GEMM
    for (int c = 0; c < 4; ++c) {
        norm_transpose_kernel<<<dim3(32, 2), 256, 0, stream>>>(
            x + (size_t)(2 * c) * QSTRIDE, xnT2);
        gemm_qkv_kernel<<<dim3(32, 12, 2), 256, 0, stream>>>(
            Wg, xnT2, q + (size_t)(2 * c) * QSTRIDE, kv + (size_t)(2 * c) * KVSTRIDE);
    }

    kstats_kernel<<<dim3(512, 8), 256, 0, stream>>>(kv, kmax, kinv, attnT);
    attn_kernel<<<dim3(8, 32, 8), 256, 0, stream>>>(kv, kmax, attnT);
    outgemm_kernel<<<dim3(32, 8, 8), 256, 0, stream>>>(q, attnT, kinv, kv);
    gemm_ffn_kernel<<<dim3(32, 4, 8), 256, 0, stream>>>(Wf, kv, ffn_b, q);
    ffnnorm_kernel<<<dim3(32, 8), 256, 0, stream>>>(q, invn2);
    final_kernel<<<dim3(1024, 8), 256, 0, stream>>>(q, invn2, ffn_g, x, out);
}

// Round 9
// 391.755 us; speedup vs baseline: 2.6344x; 1.5283x over previous
//
#include <hip/hip_runtime.h>

// ---------------------------------------------------------------------------
// MultiHeadsLinearAttention  (B=8, C=512, HEADS=8, CH=64, H=W=64 -> N=4096)
// Inputs fp32, output fp32. Compute: bf16 MFMA, fp32 accumulation.
//
// Stages:
//  W : Wg = qkv_w * g -> bf16 ; Wf = ffn_w -> bf16
//  T : per-token invx over fp32 x; xnT[p][c] = x*invx*sqrtC (bf16, k-contig)
//      chunked 2 batches at a time (grid 128x2 = 256 blocks), serial w/ C
//  C : QKV GEMM (128x128 tile, BK=64, both operands k-contiguous,
//      synchronous ushort4->LDS staging): rows<512 -> Q (ws), else K,V (d_out)
//  D : k-softmax stats (kmax,kinv)
//  E : attnP[bh][ks][d][c] = sum_{p in ks-slice} exp(k[c][p]-kmax)*v[d][p]
//      (MFMA, wave-specialized over d -> ZERO atomics, zero LDS; 8 p-partials)
//      attnP aliases the dead xnT chunk buffer.
//  F : q-softmax per token; xoT[b][p][hd] = qsm @ (sum_ks attnP * kinv)
//      (overwrites dead K region of d_out)
//  G : FFN GEMM y = ffn_b + Wf @ xoT  (overwrites Q in ws)
//  H1: invn2 = 1/||y||  ;  H2: out = y*invn2*g2*sqrtC + x  (fp32)
//
// Round-7 lesson: global_load_lds+XOR-swizzle staging diverges after graph
// replay -> synchronous staging only. Round-8 lesson: 8.4M contended global
// atomicAdds in attn = 175us wall -> partials + wave-specialization.
// LDS tiles: row stride 88 bf16 -> 16B-aligned rows, 2-way bank alias (free).
// ---------------------------------------------------------------------------

typedef __bf16 bf16_t;
typedef __bf16 bf8 __attribute__((ext_vector_type(8)));
typedef float f32x4 __attribute__((ext_vector_type(4)));

#define NC 512
#define NP 4096
#define SQRTC 22.62741699796952f
#define QSCALE 0.125f
#define LDP 88
#define QSTRIDE  ((size_t)NC * NP)      // 2097152  per-batch 512-row elems
#define KVSTRIDE ((size_t)1024 * NP)    // 4194304  per-batch kv elems (d_out)

__device__ inline unsigned short bfbits(__bf16 h) {
    return __builtin_bit_cast(unsigned short, h);
}

// ---------------------------------------------------------------------------
// W: weight convert fp32->bf16, optional per-column scale g. 4 elems/thread.
// ---------------------------------------------------------------------------
__global__ __launch_bounds__(256) void
wconv_kernel(const float* __restrict__ w, const float* __restrict__ g,
             bf16_t* __restrict__ out) {
    int i0 = (blockIdx.x * 256 + threadIdx.x) * 4;
    float4 wv = *(const float4*)&w[i0];
    if (g) {
        const float4 gv = *(const float4*)&g[i0 & 511];
        wv.x *= gv.x; wv.y *= gv.y; wv.z *= gv.z; wv.w *= gv.w;
    }
    ushort4 o;
    o.x = bfbits((__bf16)wv.x);
    o.y = bfbits((__bf16)wv.y);
    o.z = bfbits((__bf16)wv.z);
    o.w = bfbits((__bf16)wv.w);
    *(ushort4*)&out[i0] = o;
}

// ---------------------------------------------------------------------------
// T: norm + transpose, 2 batches per launch. grid(128, 2) block 256.
// Block covers 32 tokens. xnT[p][c] = x[c][p] * sqrtC/max(||x[:,p]||,1e-12)
// ---------------------------------------------------------------------------
__global__ __launch_bounds__(256) void
norm_transpose_kernel(const float* __restrict__ x, bf16_t* __restrict__ xnT) {
    const int bl = blockIdx.y;
    const int p0 = blockIdx.x * 32;
    const int t = threadIdx.x;
    const float* xb = x + (size_t)bl * QSTRIDE;
    bf16_t* ob = xnT + (size_t)bl * QSTRIDE;

    // pass 1: sumsq — 8 threads per token, 64 c each
    const int pp = t & 31;
    const int ch = (t >> 5) * 64;
    float ss = 0.f;
    for (int c = 0; c < 64; ++c) {
        float v = xb[(size_t)(ch + c) * NP + p0 + pp];
        ss += v * v;
    }
    __shared__ float sS[8][32];
    __shared__ float sInv[32];
    sS[t >> 5][pp] = ss;
    __syncthreads();
    if (t < 32) {
        float tot = 0.f;
        #pragma unroll
        for (int j = 0; j < 8; ++j) tot += sS[j][t];
        sInv[t] = SQRTC / fmaxf(sqrtf(tot), 1e-12f);
    }
    __syncthreads();

    // pass 2: 32-c x 32-p chunks through LDS transpose
    __shared__ __bf16 sT[32][40];
    for (int cc = 0; cc < 512; cc += 32) {
        #pragma unroll
        for (int j = 0; j < 4; ++j) {
            int e = t + j * 256;                 // 1024 = 32c x 32p
            int cr = e >> 5, p = e & 31;
            sT[cr][p] = (__bf16)(xb[(size_t)(cc + cr) * NP + p0 + p] * sInv[p]);
        }
        __syncthreads();
        if (t < 128) {
            int p = t >> 2, c8 = (t & 3) * 8;
            bf8 v;
            #pragma unroll
            for (int q = 0; q < 8; ++q) v[q] = sT[c8 + q][p];
            *(bf8*)&ob[(size_t)(p0 + p) * NC + cc + c8] = v;
        }
        __syncthreads();
    }
}

// ---------------------------------------------------------------------------
// C: QKV GEMM. grid(32, 12, nb) block 256 (nb batches per launch).
// A = Wg [1536][512], B = xnT [p][c] (both k-contiguous bf16).
// 128x128 tile, BK=64, 4 waves of 64x64. Synchronous ushort4 staging.
// ---------------------------------------------------------------------------
__global__ __launch_bounds__(256) void
gemm_qkv_kernel(const bf16_t* __restrict__ Wg, const bf16_t* __restrict__ xnT,
                bf16_t* __restrict__ qout, bf16_t* __restrict__ kvout) {
    const int bn = blockIdx.x, bm = blockIdx.y, b = blockIdx.z;
    const int t = threadIdx.x;
    const int w = t >> 6, ln = t & 63, quad = ln >> 4, l16 = ln & 15;
    const int wm = w >> 1, wn = w & 1;

    __shared__ __align__(16) __bf16 sA[128][LDP];
    __shared__ __align__(16) __bf16 sB[128][LDP];

    f32x4 acc[4][4] = {};
    const bf16_t* Abase = Wg + (size_t)(bm * 128) * NC;
    const bf16_t* Bbase = xnT + (size_t)b * QSTRIDE + (size_t)(bn * 128) * NC;

    for (int kt = 0; kt < 8; ++kt) {
        const int k0 = kt * 64;
        #pragma unroll
        for (int i = 0; i < 8; ++i) {
            int idx = t + i * 256;            // < 2048
            int r = idx >> 4;
            int c4 = (idx & 15) * 4;
            *(ushort4*)&sA[r][c4] = *(const ushort4*)&Abase[(size_t)r * NC + k0 + c4];
            *(ushort4*)&sB[r][c4] = *(const ushort4*)&Bbase[(size_t)r * NC + k0 + c4];
        }
        __syncthreads();
        #pragma unroll
        for (int ks = 0; ks < 2; ++ks) {
            const int kk = ks * 32;
            bf8 af[4], bfr[4];
            #pragma unroll
            for (int mi = 0; mi < 4; ++mi)
                af[mi] = *(const bf8*)&sA[wm * 64 + mi * 16 + l16][kk + quad * 8];
            #pragma unroll
            for (int ni = 0; ni < 4; ++ni)
                bfr[ni] = *(const bf8*)&sB[wn * 64 + ni * 16 + l16][kk + quad * 8];
            #pragma unroll
            for (int mi = 0; mi < 4; ++mi)
                #pragma unroll
                for (int ni = 0; ni < 4; ++ni)
                    acc[mi][ni] = __builtin_amdgcn_mfma_f32_16x16x32_bf16(
                        af[mi], bfr[ni], acc[mi][ni], 0, 0, 0);
        }
        __syncthreads();
    }

    bf16_t* qb = qout + (size_t)b * QSTRIDE;
    bf16_t* kvb = kvout + (size_t)b * KVSTRIDE;
    const int p0 = bn * 128;
    #pragma unroll
    for (int ni = 0; ni < 4; ++ni) {
        const int colL = wn * 64 + ni * 16 + l16;
        #pragma unroll
        for (int mi = 0; mi < 4; ++mi) {
            #pragma unroll
            for (int r = 0; r < 4; ++r) {
                const int row = bm * 128 + wm * 64 + mi * 16 + quad * 4 + r;
                const __bf16 val = (__bf16)acc[mi][ni][r];
                if (row < 512)
                    qb[(size_t)row * NP + p0 + colL] = val;
                else
                    kvb[(size_t)(row - 512) * NP + p0 + colL] = val;
            }
        }
    }
}

// ---------------------------------------------------------------------------
// G: FFN GEMM. grid(32, 4, 8) block 256.
// A = Wf [512][512], B = xoT [p][c] (d_out K region), out y (+bias) -> ws.
// ---------------------------------------------------------------------------
__global__ __launch_bounds__(256) void
gemm_ffn_kernel(const bf16_t* __restrict__ Wf, const bf16_t* __restrict__ xoT,
                const float* __restrict__ bias, bf16_t* __restrict__ y) {
    const int bn = blockIdx.x, bm = blockIdx.y, b = blockIdx.z;
    const int t = threadIdx.x;
    const int w = t >> 6, ln = t & 63, quad = ln >> 4, l16 = ln & 15;
    const int wm = w >> 1, wn = w & 1;

    __shared__ __align__(16) __bf16 sA[128][LDP];
    __shared__ __align__(16) __bf16 sB[128][LDP];

    f32x4 acc[4][4] = {};
    const bf16_t* Abase = Wf + (size_t)(bm * 128) * NC;
    const bf16_t* Bbase = xoT + (size_t)b * KVSTRIDE + (size_t)(bn * 128) * NC;

    for (int kt = 0; kt < 8; ++kt) {
        const int k0 = kt * 64;
        #pragma unroll
        for (int i = 0; i < 8; ++i) {
            int idx = t + i * 256;
            int r = idx >> 4;
            int c4 = (idx & 15) * 4;
            *(ushort4*)&sA[r][c4] = *(const ushort4*)&Abase[(size_t)r * NC + k0 + c4];
            *(ushort4*)&sB[r][c4] = *(const ushort4*)&Bbase[(size_t)r * NC + k0 + c4];
        }
        __syncthreads();
        #pragma unroll
        for (int ks = 0; ks < 2; ++ks) {
            const int kk = ks * 32;
            bf8 af[4], bfr[4];
            #pragma unroll
            for (int mi = 0; mi < 4; ++mi)
                af[mi] = *(const bf8*)&sA[wm * 64 + mi * 16 + l16][kk + quad * 8];
            #pragma unroll
            for (int ni = 0; ni < 4; ++ni)
                bfr[ni] = *(const bf8*)&sB[wn * 64 + ni * 16 + l16][kk + quad * 8];
            #pragma unroll
            for (int mi = 0; mi < 4; ++mi)
                #pragma unroll
                for (int ni = 0; ni < 4; ++ni)
                    acc[mi][ni] = __builtin_amdgcn_mfma_f32_16x16x32_bf16(
                        af[mi], bfr[ni], acc[mi][ni], 0, 0, 0);
        }
        __syncthreads();
    }

    bf16_t* yb = y + (size_t)b * QSTRIDE;
    const int p0 = bn * 128;
    #pragma unroll
    for (int mi = 0; mi < 4; ++mi) {
        #pragma unroll
        for (int ni = 0; ni < 4; ++ni) {
            const int col = p0 + wn * 64 + ni * 16 + l16;
            #pragma unroll
            for (int r = 0; r < 4; ++r) {
                const int row = bm * 128 + wm * 64 + mi * 16 + quad * 4 + r;
                float v = acc[mi][ni][r] + bias[row];
                yb[(size_t)row * NP + col] = (__bf16)v;
            }
        }
    }
}

// ---------------------------------------------------------------------------
// D: k-softmax stats per (b, channel) row. grid(512, 8) block 256.
// ---------------------------------------------------------------------------
__global__ __launch_bounds__(256) void
kstats_kernel(const bf16_t* __restrict__ kv, float* __restrict__ kmax,
              float* __restrict__ kinv) {
    const int oc = blockIdx.x, b = blockIdx.y;
    const int t = threadIdx.x, w = t >> 6, ln = t & 63;

    const bf16_t* row = kv + (size_t)b * KVSTRIDE + (size_t)oc * NP;
    float v[16];
    bf8 x0 = *(const bf8*)&row[t * 8];
    bf8 x1 = *(const bf8*)&row[2048 + t * 8];
    #pragma unroll
    for (int j = 0; j < 8; ++j) { v[j] = (float)x0[j]; v[8 + j] = (float)x1[j]; }

    float m = v[0];
    #pragma unroll
    for (int j = 1; j < 16; ++j) m = fmaxf(m, v[j]);
    #pragma unroll
    for (int off = 32; off > 0; off >>= 1) m = fmaxf(m, __shfl_down(m, off));
    __shared__ float sR[4];
    __shared__ float sS[4];
    if (ln == 0) sR[w] = m;
    __syncthreads();
    m = fmaxf(fmaxf(sR[0], sR[1]), fmaxf(sR[2], sR[3]));

    float s = 0.f;
    #pragma unroll
    for (int j = 0; j < 16; ++j) s += __expf(v[j] - m);
    #pragma unroll
    for (int off = 32; off > 0; off >>= 1) s += __shfl_down(s, off);
    if (ln == 0) sS[w] = s;
    __syncthreads();
    if (t == 0) {
        kmax[b * 512 + oc] = m;
        kinv[b * 512 + oc] = 1.0f / (sS[0] + sS[1] + sS[2] + sS[3]);
    }
}

// ---------------------------------------------------------------------------
// E: attnP[bh][ks][d][c] = sum_{p in slice} exp(k[c][p]-kmax[c]) * v[d][p].
// grid(8, 8, 8) block 256. Wave w owns d rows [w*16, w*16+16): no reduction,
// no atomics, no LDS. Each ks-slice covers 512 p (16 iters of 32 p).
// ---------------------------------------------------------------------------
__global__ __launch_bounds__(256) void
attn_kernel(const bf16_t* __restrict__ kv, const float* __restrict__ kmax,
            float* __restrict__ attnP) {
    const int h = blockIdx.x, ks = blockIdx.y, b = blockIdx.z;
    const int t = threadIdx.x, w = t >> 6, ln = t & 63, quad = ln >> 4, l16 = ln & 15;

    const bf16_t* Kb = kv + (size_t)b * KVSTRIDE + (size_t)(h * 64) * NP;
    const bf16_t* Vb = kv + (size_t)b * KVSTRIDE + (size_t)(512 + h * 64 + w * 16) * NP;

    float km[4];
    #pragma unroll
    for (int mi = 0; mi < 4; ++mi) km[mi] = kmax[b * 512 + h * 64 + mi * 16 + l16];

    f32x4 acc[4] = {};
    const int pbase = ks * 512 + quad * 8;
    #pragma unroll 4
    for (int it = 0; it < 16; ++it) {
        const int p0 = pbase + it * 32;
        bf8 bfr = *(const bf8*)&Vb[(size_t)l16 * NP + p0];
        #pragma unroll
        for (int mi = 0; mi < 4; ++mi) {
            bf8 kr = *(const bf8*)&Kb[(size_t)(mi * 16 + l16) * NP + p0];
            bf8 af;
            #pragma unroll
            for (int j = 0; j < 8; ++j)
                af[j] = (__bf16)__expf((float)kr[j] - km[mi]);
            acc[mi] = __builtin_amdgcn_mfma_f32_16x16x32_bf16(af, bfr, acc[mi], 0, 0, 0);
        }
    }

    // D layout: row (=c within mi-block) = quad*4+r, col (=d) = l16.
    float* outp = attnP + (((size_t)(b * 8 + h) * 8 + ks) << 12);
    #pragma unroll
    for (int mi = 0; mi < 4; ++mi) {
        float4 v;
        v.x = acc[mi][0]; v.y = acc[mi][1]; v.z = acc[mi][2]; v.w = acc[mi][3];
        *(float4*)&outp[(w * 16 + l16) * 64 + mi * 16 + quad * 4] = v;
    }
}

// ---------------------------------------------------------------------------
// F: q softmax over ch (*SCALE) then xoT[p][h*64+d] = qsm @ (attn*kinv).
// grid(32, 8, 8) block 256. attn = sum of 8 attnP partials (L2-resident).
// xoT overwrites dead K region of d_out.
// ---------------------------------------------------------------------------
__global__ __launch_bounds__(256) void
outgemm_kernel(const bf16_t* __restrict__ q, const float* __restrict__ attnP,
               const float* __restrict__ kinv, bf16_t* __restrict__ xoT) {
    const int pt = blockIdx.x, h = blockIdx.y, b = blockIdx.z;
    const int p0 = pt * 128;
    const int t = threadIdx.x, w = t >> 6, ln = t & 63, quad = ln >> 4, l16 = ln & 15;

    __shared__ __align__(16) __bf16 sQb[128][LDP];   // [p][c]
    __shared__ __align__(16) __bf16 sAt[64][LDP];    // [d][c]
    __shared__ float sMax[128], sInv[128];

    const bf16_t* qb = q + (size_t)b * QSTRIDE;
    const float* ap = attnP + (((size_t)(b * 8 + h) * 8) << 12);
    #pragma unroll
    for (int i = 0; i < 16; ++i) {
        int e = t + i * 256;             // d*64 + c
        int d = e >> 6, c = e & 63;
        float s = 0.f;
        #pragma unroll
        for (int ksi = 0; ksi < 8; ++ksi) s += ap[(ksi << 12) + e];
        sAt[d][c] = (__bf16)(s * kinv[b * 512 + h * 64 + c]);
    }
    #pragma unroll
    for (int i = 0; i < 32; ++i) {
        int e = t + i * 256;             // c*128 + p
        int c = e >> 7, p = e & 127;
        sQb[p][c] = qb[(size_t)(h * 64 + c) * NP + p0 + p];
    }
    __syncthreads();
    if (t < 128) {
        float m = -1e30f;
        #pragma unroll
        for (int c = 0; c < 64; ++c) m = fmaxf(m, (float)sQb[t][c]);
        float s = 0.f;
        #pragma unroll
        for (int c = 0; c < 64; ++c) s += __expf((float)sQb[t][c] - m);
        sMax[t] = m;
        sInv[t] = QSCALE / s;
    }
    __syncthreads();
    #pragma unroll
    for (int i = 0; i < 32; ++i) {
        int e = t + i * 256;             // p*64 + c
        int p = e >> 6, c = e & 63;
        sQb[p][c] = (__bf16)(__expf((float)sQb[p][c] - sMax[p]) * sInv[p]);
    }
    __syncthreads();

    f32x4 acc[2][4] = {};
    #pragma unroll
    for (int ksp = 0; ksp < 2; ++ksp) {
        const int kk = ksp * 32;
        bf8 af[2], bfr[4];
        #pragma unroll
        for (int mi = 0; mi < 2; ++mi)
            af[mi] = *(const bf8*)&sQb[w * 32 + mi * 16 + l16][kk + quad * 8];
        #pragma unroll
        for (int ni = 0; ni < 4; ++ni)
            bfr[ni] = *(const bf8*)&sAt[ni * 16 + l16][kk + quad * 8];
        #pragma unroll
        for (int mi = 0; mi < 2; ++mi)
            #pragma unroll
            for (int ni = 0; ni < 4; ++ni)
                acc[mi][ni] = __builtin_amdgcn_mfma_f32_16x16x32_bf16(
                    af[mi], bfr[ni], acc[mi][ni], 0, 0, 0);
    }
    bf16_t* xob = xoT + (size_t)b * KVSTRIDE;
    #pragma unroll
    for (int mi = 0; mi < 2; ++mi)
        #pragma unroll
        for (int ni = 0; ni < 4; ++ni)
            #pragma unroll
            for (int r = 0; r < 4; ++r) {
                int p = p0 + w * 32 + mi * 16 + quad * 4 + r;
                int dg = h * 64 + ni * 16 + l16;
                xob[(size_t)p * NC + dg] = (__bf16)acc[mi][ni][r];
            }
}

// ---------------------------------------------------------------------------
// H1: invn2[b][p] = 1/||y[:,p]||. grid(32, 8) block 256.
// ---------------------------------------------------------------------------
__global__ __launch_bounds__(256) void
ffnnorm_kernel(const bf16_t* __restrict__ y, float* __restrict__ invn2) {
    const int p0 = blockIdx.x * 128, b = blockIdx.y;
    const int t = threadIdx.x;
    const int p = p0 + (t & 127);
    const int obase = (t >> 7) * 256;
    const bf16_t* yb = y + (size_t)b * QSTRIDE;
    float s = 0.f;
    for (int o = 0; o < 256; ++o) {
        float v = (float)yb[(size_t)(obase + o) * NP + p];
        s += v * v;
    }
    __shared__ float sS[256];
    sS[t] = s;
    __syncthreads();
    if (t < 128)
        invn2[b * NP + p0 + t] = 1.0f / fmaxf(sqrtf(sS[t] + sS[t + 128]), 1e-12f);
}

// ---------------------------------------------------------------------------
// H2: out = y*invn2*g2*sqrtC + x (fp32 out). grid(1024, 8) block 256.
// ---------------------------------------------------------------------------
__global__ __launch_bounds__(256) void
final_kernel(const bf16_t* __restrict__ y, const float* __restrict__ invn2,
             const float* __restrict__ g2, const float* __restrict__ x,
             float* __restrict__ out) {
    const int b = blockIdx.y;
    int idx = blockIdx.x * 256 + threadIdx.x;      // [0, 262144)
    int o = idx >> 9;
    int p8 = (idx & 511) * 8;
    const bf16_t* yb = y + (size_t)b * QSTRIDE;
    const float* xb = x + (size_t)b * QSTRIDE;
    float* outb = out + (size_t)b * QSTRIDE;
    const float* inb = invn2 + (size_t)b * NP;

    bf8 yv = *(const bf8*)&yb[(size_t)o * NP + p8];
    float gv = g2[o] * SQRTC;
    float4 a = *(const float4*)&xb[(size_t)o * NP + p8];
    float4 b2 = *(const float4*)&xb[(size_t)o * NP + p8 + 4];

    float4 r0, r1;
    r0.x = (float)yv[0] * inb[p8 + 0] * gv + a.x;
    r0.y = (float)yv[1] * inb[p8 + 1] * gv + a.y;
    r0.z = (float)yv[2] * inb[p8 + 2] * gv + a.z;
    r0.w = (float)yv[3] * inb[p8 + 3] * gv + a.w;
    r1.x = (float)yv[4] * inb[p8 + 4] * gv + b2.x;
    r1.y = (float)yv[5] * inb[p8 + 5] * gv + b2.y;
    r1.z = (float)yv[6] * inb[p8 + 6] * gv + b2.z;
    r1.w = (float)yv[7] * inb[p8 + 7] * gv + b2.w;
    *(float4*)&outb[(size_t)o * NP + p8] = r0;
    *(float4*)&outb[(size_t)o * NP + p8 + 4] = r1;
}

// ---------------------------------------------------------------------------
extern "C" void kernel_launch(void* const* d_in, const int* in_sizes, int n_in,
                              void* d_out, int out_size, void* d_ws, size_t ws_size,
                              hipStream_t stream) {
    const float* x     = (const float*)d_in[0];
    const float* g     = (const float*)d_in[1];
    const float* qkv_w = (const float*)d_in[2];
    const float* ffn_w = (const float*)d_in[3];
    const float* ffn_b = (const float*)d_in[4];
    const float* ffn_g = (const float*)d_in[5];
    float* out = (float*)d_out;
    bf16_t* kv = (bf16_t*)d_out;     // 8*KVSTRIDE bf16 = 64 MiB (K,V then xoT)

    // workspace (~44.2 MB): attnP aliases xnT2 (disjoint lifetimes)
    bf16_t* q     = (bf16_t*)d_ws;                   // 8*QSTRIDE bf16 (Q, then y)
    bf16_t* xnT2  = q + 8 * QSTRIDE;                 // 2*QSTRIDE bf16 (chunk)
    float*  attnP = (float*)xnT2;                    // 64*8*4096 f32 = 8.39 MB
    bf16_t* Wg    = xnT2 + 2 * QSTRIDE;              // 786432 bf16
    bf16_t* Wf    = Wg + 786432;                     // 262144 bf16
    float*  kmax  = (float*)(Wf + 262144);           // 8*512 f32
    float*  kinv  = kmax + 8 * 512;                  // 8*512 f32
    float*  invn2 = kinv + 8 * 512;                  // 8*4096 f32

    wconv_kernel<<<dim3(768), 256, 0, stream>>>(qkv_w, g, Wg);
    wconv_kernel<<<dim3(256), 256, 0, stream>>>(ffn_w, nullptr, Wf);

    // chunked: normalize+transpose 2 batches, then their QKV GEMM
    for (int c = 0; c < 4; ++c) {
        norm_transpose_kernel<<<dim3(128, 2), 256, 0, stream>>>(
            x + (size_t)(2 * c) * QSTRIDE, xnT2);
        gemm_qkv_kernel<<<dim3(32, 12, 2), 256, 0, stream>>>(
            Wg, xnT2, q + (size_t)(2 * c) * QSTRIDE, kv + (size_t)(2 * c) * KVSTRIDE);
    }

    kstats_kernel<<<dim3(512, 8), 256, 0, stream>>>(kv, kmax, kinv);
    attn_kernel<<<dim3(8, 8, 8), 256, 0, stream>>>(kv, kmax, attnP);
    outgemm_kernel<<<dim3(32, 8, 8), 256, 0, stream>>>(q, attnP, kinv, kv);
    gemm_ffn_kernel<<<dim3(32, 4, 8), 256, 0, stream>>>(Wf, kv, ffn_b, q);
    ffnnorm_kernel<<<dim3(32, 8), 256, 0, stream>>>(q, invn2);
    final_kernel<<<dim3(1024, 8), 256, 0, stream>>>(q, invn2, ffn_g, x, out);
}